// Round 2
// baseline (341.445 us; speedup 1.0000x reference)
//
#include <hip/hip_runtime.h>
#include <hip/hip_bf16.h>
#include <math.h>

typedef __hip_bfloat16 bf16;
typedef __bf16 bf16x8 __attribute__((ext_vector_type(8)));
typedef float f32x4 __attribute__((ext_vector_type(4)));

__device__ inline __bf16 f2b(float f) {
  __hip_bfloat16 h = __float2bfloat16(f);
  return *reinterpret_cast<__bf16*>(&h);
}

// ---------------- transpose + cast: out[c][r] = bf16(in[r][c]) ----------------
__global__ void transpose_cast_k(const float* __restrict__ in, bf16* __restrict__ out,
                                 int rows, int cols) {
  __shared__ float tile[32][33];
  int c0 = blockIdx.x * 32;
  int r0 = blockIdx.y * 32;
  int tx = threadIdx.x;  // 0..31
  int ty = threadIdx.y;  // 0..7
  for (int i = ty; i < 32; i += 8)
    tile[i][tx] = in[(size_t)(r0 + i) * cols + c0 + tx];
  __syncthreads();
  for (int i = ty; i < 32; i += 8)
    out[(size_t)(c0 + i) * rows + r0 + tx] = __float2bfloat16(tile[tx][i]);
}

// ---------------- T5 relative-position bias LUT ----------------
// lut[h][r] = rel_bias[bucket(r-2048)][h], r in [0,4096). f64 bucketing to match np ref.
__global__ void bias_lut_k(const float* __restrict__ rel_bias, float* __restrict__ lut) {
  int r = blockIdx.x * blockDim.x + threadIdx.x;
  if (r >= 4096) return;
  int rel = r - 2048;
  int b = rel > 0 ? 16 : 0;
  int ar = rel < 0 ? -rel : rel;
  int idx;
  if (ar < 8) {
    idx = b + ar;
  } else {
    double t = log((double)ar / 8.0) / log(16.0) * 8.0;
    int lg = 8 + (int)t;
    if (lg > 15) lg = 15;
    idx = b + lg;
  }
  for (int h = 0; h < 16; ++h)
    lut[h * 4096 + r] = rel_bias[idx * 16 + h];
}

// ---------------- GEMM: C[M][N] = A[M][Kd] * Bt[N][Kd]^T ----------------
// AT: float (cast to bf16 during staging) or bf16. OT: float (MODE 0) or bf16.
// MODE 0: plain row-major store to C0
// MODE 1: Q projection scatter: C0[((b*16+h)*2048+s)*64+d]
// MODE 2: KV projection scatter: t=n>>10 -> K (C0) / V (C1), [((b*16+h)*2048+k)*64+d]
#define LDT 40  // padded LDS row (32 data + 8), rows stay 16B-aligned (80 B)

template <int MODE, typename AT, typename OT>
__global__ __launch_bounds__(256) void gemm_bt_k(const AT* __restrict__ A,
                                                 const bf16* __restrict__ Bt,
                                                 OT* __restrict__ C0,
                                                 OT* __restrict__ C1,
                                                 int M, int N, int Kd) {
  __shared__ __align__(16) bf16 As[128 * LDT];
  __shared__ __align__(16) bf16 Bs[128 * LDT];
  const int tid = threadIdx.x;
  const int lane = tid & 63;
  const int w = tid >> 6;
  const int wm = (w >> 1) * 64;
  const int wn = (w & 1) * 64;
  const int m0 = blockIdx.x * 128;
  const int n0 = blockIdx.y * 128;
  const int l15 = lane & 15;
  const int quad = lane >> 4;

  f32x4 acc[4][4];
#pragma unroll
  for (int i = 0; i < 4; ++i)
#pragma unroll
    for (int j = 0; j < 4; ++j) acc[i][j] = (f32x4){0.f, 0.f, 0.f, 0.f};

  for (int k0 = 0; k0 < Kd; k0 += 32) {
    __syncthreads();
#pragma unroll
    for (int rep = 0; rep < 2; ++rep) {
      int slot = tid + rep * 256;  // 0..511
      int row = slot >> 2;         // 0..127
      int kg = slot & 3;           // 0..3 (8 elems each)
      if (sizeof(AT) == 4) {       // fp32 -> bf16 on the fly
        const float* pa = (const float*)A + (size_t)(m0 + row) * Kd + k0 + kg * 8;
        float4 a0 = *(const float4*)pa;
        float4 a1 = *(const float4*)(pa + 4);
        bf16x8 v;
        v[0] = f2b(a0.x); v[1] = f2b(a0.y); v[2] = f2b(a0.z); v[3] = f2b(a0.w);
        v[4] = f2b(a1.x); v[5] = f2b(a1.y); v[6] = f2b(a1.z); v[7] = f2b(a1.w);
        *(bf16x8*)(As + row * LDT + kg * 8) = v;
      } else {
        uint4 va = *(const uint4*)((const bf16*)A + (size_t)(m0 + row) * Kd + k0 + kg * 8);
        *(uint4*)(As + row * LDT + kg * 8) = va;
      }
      uint4 vb = *(const uint4*)(Bt + (size_t)(n0 + row) * Kd + k0 + kg * 8);
      *(uint4*)(Bs + row * LDT + kg * 8) = vb;
    }
    __syncthreads();
    bf16x8 af[4], bfr[4];
#pragma unroll
    for (int i = 0; i < 4; ++i)
      af[i] = *(const bf16x8*)(As + (wm + i * 16 + l15) * LDT + quad * 8);
#pragma unroll
    for (int j = 0; j < 4; ++j)
      bfr[j] = *(const bf16x8*)(Bs + (wn + j * 16 + l15) * LDT + quad * 8);
#pragma unroll
    for (int i = 0; i < 4; ++i)
#pragma unroll
      for (int j = 0; j < 4; ++j)
        acc[i][j] = __builtin_amdgcn_mfma_f32_16x16x32_bf16(af[i], bfr[j], acc[i][j], 0, 0, 0);
  }

  // epilogue: C/D layout col=lane&15, row=quad*4+reg
#pragma unroll
  for (int i = 0; i < 4; ++i) {
#pragma unroll
    for (int j = 0; j < 4; ++j) {
#pragma unroll
      for (int r = 0; r < 4; ++r) {
        int gm = m0 + wm + i * 16 + quad * 4 + r;
        int gn = n0 + wn + j * 16 + l15;
        float fv = acc[i][j][r];
        if (MODE == 0) {
          C0[(size_t)gm * N + gn] = (OT)fv;
        } else if (MODE == 1) {
          int b = gm >> 11, s = gm & 2047;
          int h = gn >> 6, d = gn & 63;
          C0[((((size_t)b * 16 + h) * 2048 + s) << 6) + d] = (OT)fv;
        } else {
          int b = gm >> 11, kp = gm & 2047;
          int t = gn >> 10, h = (gn >> 6) & 15, d = gn & 63;
          OT* dst = (t == 0) ? C0 : C1;
          dst[((((size_t)b * 16 + h) * 2048 + kp) << 6) + d] = (OT)fv;
        }
      }
    }
  }
}

// ---------------- fused attention with online softmax + rel bias ----------------
// grid: (S/64, B*H). block 256 = 4 waves; wave w owns q-rows [qb+w*16, qb+w*16+16)
__global__ __launch_bounds__(256) void attn_k(const bf16* __restrict__ Qb,
                                              const bf16* __restrict__ Kb,
                                              const bf16* __restrict__ Vb,
                                              const float* __restrict__ lut,
                                              bf16* __restrict__ Ob) {
  __shared__ float lbias[2112];
  __shared__ __align__(16) bf16 Ks[64 * 72];       // [kk][d], rows padded to 72
  __shared__ __align__(16) bf16 Vs[64 * 72];       // transposed: [d][kk]
  __shared__ __align__(16) bf16 Ps[4][16 * 72];    // per-wave P, [m][kk]

  const int tid = threadIdx.x;
  const int lane = tid & 63;
  const int w = tid >> 6;
  const int l15 = lane & 15;
  const int quad = lane >> 4;

  const int qt = blockIdx.x;   // 0..31
  const int bh = blockIdx.y;   // 0..31
  const int h = bh & 15;
  const int b = bh >> 4;
  const int qb = qt * 64;

  // stage bias LUT slice: local index li = (k - q) + 2048 - s0, li in [0, 2111)
  const int s0 = 2048 - qb - 63;
  for (int t = tid; t < 2111; t += 256) lbias[t] = lut[h * 4096 + s0 + t];

  const size_t base = (size_t)bh * 2048 * 64;

  // Q fragments (A-operand layout), held in registers for the whole kernel
  const int qrow_f = qb + w * 16 + l15;
  bf16x8 qf0 = *(const bf16x8*)(Qb + base + (size_t)qrow_f * 64 + quad * 8);
  bf16x8 qf1 = *(const bf16x8*)(Qb + base + (size_t)qrow_f * 64 + 32 + quad * 8);

  f32x4 oacc[4];
#pragma unroll
  for (int j = 0; j < 4; ++j) oacc[j] = (f32x4){0.f, 0.f, 0.f, 0.f};
  float m_run[4], l_run[4];
#pragma unroll
  for (int r = 0; r < 4; ++r) { m_run[r] = -INFINITY; l_run[r] = 0.f; }

  for (int kt = 0; kt < 2048; kt += 64) {
    __syncthreads();  // protect Ks/Vs/Ps from prior-iteration readers
    // stage K tile [64 kk][64 d] -> Ks rows (vectorized, coalesced)
#pragma unroll
    for (int rep = 0; rep < 2; ++rep) {
      int slot = tid + rep * 256;  // 0..511
      int kk = slot >> 3, dg = slot & 7;
      uint4 v = *(const uint4*)(Kb + base + (size_t)(kt + kk) * 64 + dg * 8);
      *(uint4*)(Ks + kk * 72 + dg * 8) = v;
    }
    // stage V tile transposed -> Vs[d][kk]
#pragma unroll
    for (int rep = 0; rep < 2; ++rep) {
      int slot = tid + rep * 256;
      int d0 = (slot >> 6) * 8, kk = slot & 63;
      uint4 v = *(const uint4*)(Vb + base + (size_t)(kt + kk) * 64 + d0);
      const bf16* pv = (const bf16*)&v;
#pragma unroll
      for (int i = 0; i < 8; ++i) Vs[(d0 + i) * 72 + kk] = pv[i];
    }
    __syncthreads();

    // S = Q K^T for this wave's 16 rows x 64 keys
    f32x4 sacc[4];
#pragma unroll
    for (int j = 0; j < 4; ++j) {
      bf16x8 kf0 = *(const bf16x8*)(Ks + (j * 16 + l15) * 72 + quad * 8);
      bf16x8 kf1 = *(const bf16x8*)(Ks + (j * 16 + l15) * 72 + 32 + quad * 8);
      f32x4 a = (f32x4){0.f, 0.f, 0.f, 0.f};
      a = __builtin_amdgcn_mfma_f32_16x16x32_bf16(qf0, kf0, a, 0, 0, 0);
      a = __builtin_amdgcn_mfma_f32_16x16x32_bf16(qf1, kf1, a, 0, 0, 0);
      sacc[j] = a;
    }

    // bias add + per-row max (each 16-lane quarter owns 4 q-rows)
    float rmax[4];
#pragma unroll
    for (int r = 0; r < 4; ++r) rmax[r] = -INFINITY;
#pragma unroll
    for (int j = 0; j < 4; ++j) {
      int libase = kt + j * 16 + l15 - w * 16 - quad * 4 + 63;
#pragma unroll
      for (int r = 0; r < 4; ++r) {
        float s = sacc[j][r] + lbias[libase - r];
        sacc[j][r] = s;
        rmax[r] = fmaxf(rmax[r], s);
      }
    }
#pragma unroll
    for (int off = 8; off > 0; off >>= 1)
#pragma unroll
      for (int r = 0; r < 4; ++r) rmax[r] = fmaxf(rmax[r], __shfl_xor(rmax[r], off, 16));

    float alpha[4], rsum[4];
#pragma unroll
    for (int r = 0; r < 4; ++r) {
      float mnew = fmaxf(m_run[r], rmax[r]);
      alpha[r] = __expf(m_run[r] - mnew);  // exp(-inf)=0 on first tile
      float sum = 0.f;
#pragma unroll
      for (int j = 0; j < 4; ++j) {
        float p = __expf(sacc[j][r] - mnew);
        sacc[j][r] = p;
        sum += p;
      }
      rsum[r] = sum;
      m_run[r] = mnew;
    }
#pragma unroll
    for (int off = 8; off > 0; off >>= 1)
#pragma unroll
      for (int r = 0; r < 4; ++r) rsum[r] += __shfl_xor(rsum[r], off, 16);
#pragma unroll
    for (int r = 0; r < 4; ++r) l_run[r] = l_run[r] * alpha[r] + rsum[r];

    // write P (C-layout) to LDS, re-read in A-operand layout
#pragma unroll
    for (int j = 0; j < 4; ++j)
#pragma unroll
      for (int r = 0; r < 4; ++r)
        Ps[w][(quad * 4 + r) * 72 + j * 16 + l15] = __float2bfloat16(sacc[j][r]);

    // rescale O accumulator
#pragma unroll
    for (int j = 0; j < 4; ++j)
#pragma unroll
      for (int r = 0; r < 4; ++r) oacc[j][r] *= alpha[r];

    __syncthreads();  // make Ps visible

    bf16x8 pf0 = *(const bf16x8*)(&Ps[w][l15 * 72 + quad * 8]);
    bf16x8 pf1 = *(const bf16x8*)(&Ps[w][l15 * 72 + 32 + quad * 8]);
#pragma unroll
    for (int dj = 0; dj < 4; ++dj) {
      bf16x8 vf0 = *(const bf16x8*)(Vs + (dj * 16 + l15) * 72 + quad * 8);
      bf16x8 vf1 = *(const bf16x8*)(Vs + (dj * 16 + l15) * 72 + 32 + quad * 8);
      oacc[dj] = __builtin_amdgcn_mfma_f32_16x16x32_bf16(pf0, vf0, oacc[dj], 0, 0, 0);
      oacc[dj] = __builtin_amdgcn_mfma_f32_16x16x32_bf16(pf1, vf1, oacc[dj], 0, 0, 0);
    }
  }

  // epilogue: O / l -> Ob[b][s][h*64+d]  (bf16 intermediate)
  float inv[4];
#pragma unroll
  for (int r = 0; r < 4; ++r) inv[r] = 1.0f / l_run[r];
#pragma unroll
  for (int dj = 0; dj < 4; ++dj) {
#pragma unroll
    for (int r = 0; r < 4; ++r) {
      int qrow = qb + w * 16 + quad * 4 + r;
      int d = dj * 16 + l15;
      Ob[((size_t)(b * 2048 + qrow)) * 1024 + h * 64 + d] =
          __float2bfloat16(oacc[dj][r] * inv[r]);
    }
  }
}

// ---------------- launch ----------------
extern "C" void kernel_launch(void* const* d_in, const int* in_sizes, int n_in,
                              void* d_out, int out_size, void* d_ws, size_t ws_size,
                              hipStream_t stream) {
  const float* hidden = (const float*)d_in[0];  // [2,2048,1024] fp32
  const float* kvs    = (const float*)d_in[1];  // [2,2048,1024] fp32
  const float* Wq     = (const float*)d_in[2];  // [1024,1024]   fp32
  const float* Wkv    = (const float*)d_in[3];  // [1024,2048]   fp32
  const float* Wo     = (const float*)d_in[4];  // [1024,1024]   fp32
  const float* relb   = (const float*)d_in[5];  // [32,16]       fp32
  float* out = (float*)d_out;                   // [2,2048,1024] fp32

  char* ws = (char*)d_ws;
  bf16* WqT  = (bf16*)(ws + (size_t)0);          // 2 MB   [1024][1024] bf16
  bf16* WkvT = (bf16*)(ws + (size_t)(2 << 20));  // 4 MB   [2048][1024] bf16
  bf16* WoT  = (bf16*)(ws + (size_t)(6 << 20));  // 2 MB
  bf16* Qb   = (bf16*)(ws + (size_t)(8 << 20));  // 8 MB   [B,H,S,D]
  bf16* Kb   = (bf16*)(ws + (size_t)(16 << 20)); // 8 MB   [B,H,K,D]
  bf16* Vb   = (bf16*)(ws + (size_t)(24 << 20)); // 8 MB   [B,H,K,D]
  bf16* Ob   = (bf16*)(ws + (size_t)(32 << 20)); // 8 MB   [B,S,E]
  float* LUT = (float*)(ws + (size_t)(40 << 20));// 256 KB [H][4096]

  dim3 tb(32, 8);
  transpose_cast_k<<<dim3(32, 32), tb, 0, stream>>>(Wq, WqT, 1024, 1024);
  transpose_cast_k<<<dim3(64, 32), tb, 0, stream>>>(Wkv, WkvT, 1024, 2048);
  transpose_cast_k<<<dim3(32, 32), tb, 0, stream>>>(Wo, WoT, 1024, 1024);
  bias_lut_k<<<16, 256, 0, stream>>>(relb, LUT);

  // Q = hidden @ Wq  -> [B,H,S,D]
  gemm_bt_k<1, float, bf16><<<dim3(32, 8), 256, 0, stream>>>(hidden, WqT, Qb, (bf16*)nullptr, 4096, 1024, 1024);
  // KV = kv_states @ Wkv -> K,V [B,H,K,D]
  gemm_bt_k<2, float, bf16><<<dim3(32, 16), 256, 0, stream>>>(kvs, WkvT, Kb, Vb, 4096, 2048, 1024);
  // attention
  attn_k<<<dim3(32, 32), 256, 0, stream>>>(Qb, Kb, Vb, LUT, Ob);
  // out = O @ Wo (fp32 store)
  gemm_bt_k<0, bf16, float><<<dim3(32, 8), 256, 0, stream>>>(Ob, WoT, out, (float*)nullptr, 4096, 1024, 1024);
}

// Round 3
// 319.828 us; speedup vs baseline: 1.0676x; 1.0676x over previous
//
#include <hip/hip_runtime.h>
#include <hip/hip_bf16.h>
#include <math.h>

typedef __hip_bfloat16 bf16;
typedef __bf16 bf16x8 __attribute__((ext_vector_type(8)));
typedef float f32x4 __attribute__((ext_vector_type(4)));
typedef unsigned short us4 __attribute__((ext_vector_type(4)));

__device__ inline __bf16 f2b(float f) {
  __hip_bfloat16 h = __float2bfloat16(f);
  return *reinterpret_cast<__bf16*>(&h);
}
__device__ inline unsigned short b2u(float f) {
  __hip_bfloat16 h = __float2bfloat16(f);
  return *reinterpret_cast<unsigned short*>(&h);
}

// async global->LDS, 16B per lane; lds base must be wave-uniform
__device__ inline void async16(const bf16* g, bf16* l) {
  __builtin_amdgcn_global_load_lds(
      (const __attribute__((address_space(1))) unsigned int*)g,
      (__attribute__((address_space(3))) unsigned int*)l, 16, 0, 0);
}

// ---------------- fp32 -> bf16 cast (vectorized) ----------------
__global__ void cast_k(const float* __restrict__ in, bf16* __restrict__ out, int n) {
  int i = (blockIdx.x * 256 + threadIdx.x) * 8;
  if (i >= n) return;
  float4 a0 = *(const float4*)(in + i);
  float4 a1 = *(const float4*)(in + i + 4);
  bf16x8 v;
  v[0] = f2b(a0.x); v[1] = f2b(a0.y); v[2] = f2b(a0.z); v[3] = f2b(a0.w);
  v[4] = f2b(a1.x); v[5] = f2b(a1.y); v[6] = f2b(a1.z); v[7] = f2b(a1.w);
  *(bf16x8*)(out + i) = v;
}

// ---------------- transpose + cast: out[c][r] = bf16(in[r][c]) ----------------
__global__ void transpose_cast_k(const float* __restrict__ in, bf16* __restrict__ out,
                                 int rows, int cols) {
  __shared__ float tile[32][33];
  int c0 = blockIdx.x * 32;
  int r0 = blockIdx.y * 32;
  int tx = threadIdx.x;
  int ty = threadIdx.y;
  for (int i = ty; i < 32; i += 8)
    tile[i][tx] = in[(size_t)(r0 + i) * cols + c0 + tx];
  __syncthreads();
  for (int i = ty; i < 32; i += 8)
    out[(size_t)(c0 + i) * rows + r0 + tx] = __float2bfloat16(tile[tx][i]);
}

// ---------------- T5 relative-position bias LUT (f64 bucketing = np ref) ----------------
__global__ void bias_lut_k(const float* __restrict__ rel_bias, float* __restrict__ lut) {
  int r = blockIdx.x * blockDim.x + threadIdx.x;
  if (r >= 4096) return;
  int rel = r - 2048;
  int b = rel > 0 ? 16 : 0;
  int ar = rel < 0 ? -rel : rel;
  int idx;
  if (ar < 8) {
    idx = b + ar;
  } else {
    double t = log((double)ar / 8.0) / log(16.0) * 8.0;
    int lg = 8 + (int)t;
    if (lg > 15) lg = 15;
    idx = b + lg;
  }
  for (int h = 0; h < 16; ++h)
    lut[h * 4096 + r] = rel_bias[idx * 16 + h];
}

// ---------------- GEMM (m97 structure): C[M][N] = A[M][Kd] * Bt[N][Kd]^T ----------------
// bf16 A and Bt; unpadded 128x32 LDS tiles staged via global_load_lds x16.
// MODE 0: fp32 row-major store to C0
// MODE 1: Q scatter: C0[((b*16+h)*2048+s)*64+d] (bf16)
// MODE 2: KV: n<1024 -> K to C0 [b,h,k,d]; n>=1024 -> V to C1 transposed [b,h,d,k]
template <int MODE, typename OT>
__global__ __launch_bounds__(256) void gemm_bt_k(const bf16* __restrict__ A,
                                                 const bf16* __restrict__ Bt,
                                                 OT* __restrict__ C0,
                                                 bf16* __restrict__ C1,
                                                 int M, int N, int Kd) {
  __shared__ __align__(16) bf16 As[128 * 32];
  __shared__ __align__(16) bf16 Bs[128 * 32];
  const int tid = threadIdx.x;
  const int lane = tid & 63;
  const int w = tid >> 6;
  const int wm = (w >> 1) * 64;
  const int wn = (w & 1) * 64;
  const int m0 = blockIdx.x * 128;
  const int n0 = blockIdx.y * 128;
  const int l15 = lane & 15;
  const int quad = lane >> 4;
  const int srow = lane >> 2;   // 0..15 within 16-row segment
  const int skg = lane & 3;     // 16B chunk within 64B row

  f32x4 acc[4][4];
#pragma unroll
  for (int i = 0; i < 4; ++i)
#pragma unroll
    for (int j = 0; j < 4; ++j) acc[i][j] = (f32x4){0.f, 0.f, 0.f, 0.f};

  for (int k0 = 0; k0 < Kd; k0 += 32) {
    __syncthreads();
#pragma unroll
    for (int rep = 0; rep < 2; ++rep) {
      int seg = w * 2 + rep;  // 0..7, 16 rows each
      async16(A + (size_t)(m0 + seg * 16 + srow) * Kd + k0 + skg * 8, As + seg * 512);
      async16(Bt + (size_t)(n0 + seg * 16 + srow) * Kd + k0 + skg * 8, Bs + seg * 512);
    }
    __syncthreads();
    bf16x8 af[4], bfr[4];
#pragma unroll
    for (int i = 0; i < 4; ++i)
      af[i] = *(const bf16x8*)(As + (wm + i * 16 + l15) * 32 + quad * 8);
#pragma unroll
    for (int j = 0; j < 4; ++j)
      bfr[j] = *(const bf16x8*)(Bs + (wn + j * 16 + l15) * 32 + quad * 8);
#pragma unroll
    for (int i = 0; i < 4; ++i)
#pragma unroll
      for (int j = 0; j < 4; ++j)
        acc[i][j] = __builtin_amdgcn_mfma_f32_16x16x32_bf16(af[i], bfr[j], acc[i][j], 0, 0, 0);
  }

  // epilogue: C/D layout col=lane&15, row=quad*4+reg
  if (MODE == 2 && n0 >= 1024) {
    // V half -> transposed store, 4 consecutive k packed per 8B store
#pragma unroll
    for (int i = 0; i < 4; ++i) {
      int gmb = m0 + wm + i * 16 + quad * 4;
      int b = gmb >> 11, kp = gmb & 2047;
#pragma unroll
      for (int j = 0; j < 4; ++j) {
        int gn = n0 + wn + j * 16 + l15;
        int h = (gn >> 6) & 15, d = gn & 63;
        us4 pk;
#pragma unroll
        for (int r = 0; r < 4; ++r) pk[r] = b2u(acc[i][j][r]);
        *(us4*)(C1 + ((((size_t)b * 16 + h) * 64 + d) << 11) + kp) = pk;
      }
    }
    return;
  }
#pragma unroll
  for (int i = 0; i < 4; ++i) {
#pragma unroll
    for (int j = 0; j < 4; ++j) {
#pragma unroll
      for (int r = 0; r < 4; ++r) {
        int gm = m0 + wm + i * 16 + quad * 4 + r;
        int gn = n0 + wn + j * 16 + l15;
        float fv = acc[i][j][r];
        if (MODE == 0) {
          C0[(size_t)gm * N + gn] = (OT)fv;
        } else if (MODE == 1) {
          int b = gm >> 11, s = gm & 2047;
          int h = gn >> 6, d = gn & 63;
          C0[((((size_t)b * 16 + h) * 2048 + s) << 6) + d] = (OT)fv;
        } else {  // MODE 2, K half
          int b = gm >> 11, kp = gm & 2047;
          int h = (gn >> 6) & 15, d = gn & 63;
          C0[((((size_t)b * 16 + h) * 2048 + kp) << 6) + d] = (OT)fv;
        }
      }
    }
  }
}

// ---------------- fused attention: 128 q-rows x 128-key tiles ----------------
// grid (S/128, B*H), 256 threads = 4 waves; wave w owns 32 q-rows (2 m-frags)
__global__ __launch_bounds__(256) void attn_k(const bf16* __restrict__ Qb,
                                              const bf16* __restrict__ Kb,
                                              const bf16* __restrict__ Vt,
                                              const float* __restrict__ lut,
                                              bf16* __restrict__ Ob) {
  __shared__ bf16 lbias[2176];
  __shared__ __align__(16) bf16 Ks[128 * 72];     // [kk][d] padded
  __shared__ __align__(16) bf16 Vs[64 * 136];     // [d][kk] padded
  __shared__ __align__(16) bf16 Ps[4][32 * 136];  // per-wave P [m][kk]

  const int tid = threadIdx.x;
  const int lane = tid & 63;
  const int w = tid >> 6;
  const int l15 = lane & 15;
  const int quad = lane >> 4;

  const int qt = blockIdx.x;  // 0..15
  const int bh = blockIdx.y;  // 0..31
  const int h = bh & 15;
  const int b = bh >> 4;
  const int qb = qt * 128;

  // bias slice: lbias[li], li = (k - q) + qb + 127, li in [0,2175)
  const int s0 = 1921 - qb;
  for (int t = tid; t < 2175; t += 256) lbias[t] = __float2bfloat16(lut[h * 4096 + s0 + t]);

  const size_t base = (size_t)bh * 2048 * 64;   // K rows base
  const size_t vbase = (size_t)bh * 64 * 2048;  // Vt rows base

  // Q fragments: 2 m-frags x 2 k-chunks, held in registers
  bf16x8 qf[2][2];
#pragma unroll
  for (int m = 0; m < 2; ++m) {
    int qrow = qb + w * 32 + m * 16 + l15;
    qf[m][0] = *(const bf16x8*)(Qb + base + (size_t)qrow * 64 + quad * 8);
    qf[m][1] = *(const bf16x8*)(Qb + base + (size_t)qrow * 64 + 32 + quad * 8);
  }

  f32x4 oacc[2][4];
#pragma unroll
  for (int m = 0; m < 2; ++m)
#pragma unroll
    for (int j = 0; j < 4; ++j) oacc[m][j] = (f32x4){0.f, 0.f, 0.f, 0.f};
  float m_run[2][4], l_run[2][4];
#pragma unroll
  for (int m = 0; m < 2; ++m)
#pragma unroll
    for (int r = 0; r < 4; ++r) { m_run[m][r] = -INFINITY; l_run[m][r] = 0.f; }

  for (int kt = 0; kt < 2048; kt += 128) {
    __syncthreads();
    // stage K tile [128 kk][64 d]
#pragma unroll
    for (int rep = 0; rep < 4; ++rep) {
      int slot = tid + rep * 256;  // 0..1023
      int kk = slot >> 3, dg = slot & 7;
      uint4 v = *(const uint4*)(Kb + base + (size_t)(kt + kk) * 64 + dg * 8);
      *(uint4*)(Ks + kk * 72 + dg * 8) = v;
    }
    // stage V tile from transposed global: Vs[d][kk]
#pragma unroll
    for (int rep = 0; rep < 4; ++rep) {
      int slot = tid + rep * 256;
      int d = slot >> 4, c = slot & 15;
      uint4 v = *(const uint4*)(Vt + vbase + (size_t)d * 2048 + kt + c * 8);
      *(uint4*)(Vs + d * 136 + c * 8) = v;
    }
    __syncthreads();

    // S = Q K^T: 2 m-frags x 8 key-tiles
    f32x4 sacc[2][8];
#pragma unroll
    for (int j = 0; j < 8; ++j) {
      bf16x8 kf0 = *(const bf16x8*)(Ks + (j * 16 + l15) * 72 + quad * 8);
      bf16x8 kf1 = *(const bf16x8*)(Ks + (j * 16 + l15) * 72 + 32 + quad * 8);
#pragma unroll
      for (int m = 0; m < 2; ++m) {
        f32x4 a = (f32x4){0.f, 0.f, 0.f, 0.f};
        a = __builtin_amdgcn_mfma_f32_16x16x32_bf16(qf[m][0], kf0, a, 0, 0, 0);
        a = __builtin_amdgcn_mfma_f32_16x16x32_bf16(qf[m][1], kf1, a, 0, 0, 0);
        sacc[m][j] = a;
      }
    }

    // bias + online softmax per m-frag (16-lane quarters own 4 q-rows)
#pragma unroll
    for (int m = 0; m < 2; ++m) {
      float rmax[4];
#pragma unroll
      for (int r = 0; r < 4; ++r) rmax[r] = -INFINITY;
#pragma unroll
      for (int j = 0; j < 8; ++j) {
        int libase = kt + j * 16 + l15 - w * 32 - m * 16 - quad * 4 + 127;
#pragma unroll
        for (int r = 0; r < 4; ++r) {
          float s = sacc[m][j][r] + __bfloat162float(lbias[libase - r]);
          sacc[m][j][r] = s;
          rmax[r] = fmaxf(rmax[r], s);
        }
      }
#pragma unroll
      for (int off = 8; off > 0; off >>= 1)
#pragma unroll
        for (int r = 0; r < 4; ++r) rmax[r] = fmaxf(rmax[r], __shfl_xor(rmax[r], off, 16));

      float alpha[4], rsum[4];
#pragma unroll
      for (int r = 0; r < 4; ++r) {
        float mnew = fmaxf(m_run[m][r], rmax[r]);
        alpha[r] = __expf(m_run[m][r] - mnew);
        float sum = 0.f;
#pragma unroll
        for (int j = 0; j < 8; ++j) {
          float p = __expf(sacc[m][j][r] - mnew);
          sacc[m][j][r] = p;
          sum += p;
        }
        rsum[r] = sum;
        m_run[m][r] = mnew;
      }
#pragma unroll
      for (int off = 8; off > 0; off >>= 1)
#pragma unroll
        for (int r = 0; r < 4; ++r) rsum[r] += __shfl_xor(rsum[r], off, 16);
#pragma unroll
      for (int r = 0; r < 4; ++r) l_run[m][r] = l_run[m][r] * alpha[r] + rsum[r];

      // P -> LDS (C-layout write)
#pragma unroll
      for (int j = 0; j < 8; ++j)
#pragma unroll
        for (int r = 0; r < 4; ++r)
          Ps[w][(m * 16 + quad * 4 + r) * 136 + j * 16 + l15] =
              __float2bfloat16(sacc[m][j][r]);

      // rescale O
#pragma unroll
      for (int j = 0; j < 4; ++j)
#pragma unroll
        for (int r = 0; r < 4; ++r) oacc[m][j][r] *= alpha[r];
    }

    __syncthreads();

    // O += P V : P A-frags from LDS, V B-frags from Vs
    bf16x8 pf[2][4];
#pragma unroll
    for (int m = 0; m < 2; ++m)
#pragma unroll
      for (int c = 0; c < 4; ++c)
        pf[m][c] = *(const bf16x8*)(&Ps[w][(m * 16 + l15) * 136 + c * 32 + quad * 8]);
#pragma unroll
    for (int dj = 0; dj < 4; ++dj) {
#pragma unroll
      for (int c = 0; c < 4; ++c) {
        bf16x8 vf = *(const bf16x8*)(Vs + (dj * 16 + l15) * 136 + c * 32 + quad * 8);
#pragma unroll
        for (int m = 0; m < 2; ++m)
          oacc[m][dj] = __builtin_amdgcn_mfma_f32_16x16x32_bf16(pf[m][c], vf, oacc[m][dj], 0, 0, 0);
      }
    }
  }

  // epilogue: O / l -> Ob[b][s][h*64+d]
#pragma unroll
  for (int m = 0; m < 2; ++m) {
    float inv[4];
#pragma unroll
    for (int r = 0; r < 4; ++r) inv[r] = 1.0f / l_run[m][r];
#pragma unroll
    for (int dj = 0; dj < 4; ++dj)
#pragma unroll
      for (int r = 0; r < 4; ++r) {
        int qrow = qb + w * 32 + m * 16 + quad * 4 + r;
        int d = dj * 16 + l15;
        Ob[((size_t)(b * 2048 + qrow)) * 1024 + h * 64 + d] =
            __float2bfloat16(oacc[m][dj][r] * inv[r]);
      }
  }
}

// ---------------- launch ----------------
extern "C" void kernel_launch(void* const* d_in, const int* in_sizes, int n_in,
                              void* d_out, int out_size, void* d_ws, size_t ws_size,
                              hipStream_t stream) {
  const float* hidden = (const float*)d_in[0];
  const float* kvs    = (const float*)d_in[1];
  const float* Wq     = (const float*)d_in[2];
  const float* Wkv    = (const float*)d_in[3];
  const float* Wo     = (const float*)d_in[4];
  const float* relb   = (const float*)d_in[5];
  float* out = (float*)d_out;

  char* ws = (char*)d_ws;
  bf16* WqT  = (bf16*)(ws + (size_t)0);           // 2 MB
  bf16* WkvT = (bf16*)(ws + ((size_t)2 << 20));   // 4 MB
  bf16* WoT  = (bf16*)(ws + ((size_t)6 << 20));   // 2 MB
  bf16* hbf  = (bf16*)(ws + ((size_t)8 << 20));   // 8 MB (dead after Q GEMM)
  bf16* Kb   = (bf16*)(ws + ((size_t)8 << 20));   // 8 MB (reuses hbf region)
  bf16* kbf  = (bf16*)(ws + ((size_t)16 << 20));  // 8 MB (dead after KV GEMM)
  bf16* Ob   = (bf16*)(ws + ((size_t)16 << 20));  // 8 MB (reuses kbf region)
  bf16* Qb   = (bf16*)(ws + ((size_t)24 << 20));  // 8 MB
  bf16* Vt   = (bf16*)(ws + ((size_t)32 << 20));  // 8 MB [b,h,d,k]
  float* LUT = (float*)(ws + ((size_t)40 << 20)); // 256 KB

  dim3 tb(32, 8);
  transpose_cast_k<<<dim3(32, 32), tb, 0, stream>>>(Wq, WqT, 1024, 1024);
  transpose_cast_k<<<dim3(64, 32), tb, 0, stream>>>(Wkv, WkvT, 1024, 2048);
  transpose_cast_k<<<dim3(32, 32), tb, 0, stream>>>(Wo, WoT, 1024, 1024);
  bias_lut_k<<<16, 256, 0, stream>>>(relb, LUT);
  cast_k<<<2048, 256, 0, stream>>>(hidden, hbf, 4194304);
  cast_k<<<2048, 256, 0, stream>>>(kvs, kbf, 4194304);

  // Q = hidden @ Wq -> [B,H,S,D]
  gemm_bt_k<1, bf16><<<dim3(32, 8), 256, 0, stream>>>(hbf, WqT, Qb, (bf16*)nullptr, 4096, 1024, 1024);
  // K,V = kvs @ Wkv -> Kb [b,h,k,d], Vt [b,h,d,k]
  gemm_bt_k<2, bf16><<<dim3(32, 16), 256, 0, stream>>>(kbf, WkvT, Kb, Vt, 4096, 2048, 1024);
  // attention -> Ob [B,S,E]
  attn_k<<<dim3(16, 32), 256, 0, stream>>>(Qb, Kb, Vt, LUT, Ob);
  // out = Ob @ Wo (fp32)
  gemm_bt_k<0, float><<<dim3(32, 8), 256, 0, stream>>>(Ob, WoT, out, (bf16*)nullptr, 4096, 1024, 1024);
}

// Round 4
// 272.045 us; speedup vs baseline: 1.2551x; 1.1756x over previous
//
#include <hip/hip_runtime.h>
#include <hip/hip_bf16.h>
#include <math.h>

typedef __hip_bfloat16 bf16;
typedef __bf16 bf16x4 __attribute__((ext_vector_type(4)));
typedef __bf16 bf16x8 __attribute__((ext_vector_type(8)));
typedef float f32x4 __attribute__((ext_vector_type(4)));
typedef float f32x16 __attribute__((ext_vector_type(16)));
typedef unsigned short us4 __attribute__((ext_vector_type(4)));

__device__ inline __bf16 f2b(float f) {
  __hip_bfloat16 h = __float2bfloat16(f);
  return *reinterpret_cast<__bf16*>(&h);
}
__device__ inline unsigned short b2u(float f) {
  __hip_bfloat16 h = __float2bfloat16(f);
  return *reinterpret_cast<unsigned short*>(&h);
}
// 16B logical read as two 8B reads (safe at 8B alignment; 2-way-bank strides)
__device__ inline bf16x8 ld16(const bf16* p) {
  bf16x4 lo = *(const bf16x4*)p;
  bf16x4 hi = *(const bf16x4*)(p + 4);
  return __builtin_shufflevector(lo, hi, 0, 1, 2, 3, 4, 5, 6, 7);
}
__device__ inline void st16(bf16* p, uint4 v) {
  *(uint2*)p = make_uint2(v.x, v.y);
  *(uint2*)(p + 4) = make_uint2(v.z, v.w);
}
// async global->LDS, 16B/lane, lds addr = wave-uniform base + lane*16
__device__ inline void async16(const bf16* g, bf16* l) {
  __builtin_amdgcn_global_load_lds(
      (const __attribute__((address_space(1))) unsigned int*)g,
      (__attribute__((address_space(3))) unsigned int*)l, 16, 0, 0);
}

// ---------------- transpose + cast: out[c][r] = bf16(in[r][c]) ----------------
__global__ void transpose_cast_k(const float* __restrict__ in, bf16* __restrict__ out,
                                 int rows, int cols) {
  __shared__ float tile[32][33];
  int c0 = blockIdx.x * 32;
  int r0 = blockIdx.y * 32;
  int tx = threadIdx.x;
  int ty = threadIdx.y;
  for (int i = ty; i < 32; i += 8)
    tile[i][tx] = in[(size_t)(r0 + i) * cols + c0 + tx];
  __syncthreads();
  for (int i = ty; i < 32; i += 8)
    out[(size_t)(c0 + i) * rows + r0 + tx] = __float2bfloat16(tile[tx][i]);
}

// ---------------- T5 bias LUT (f64 bucketing = np ref) ----------------
__global__ void bias_lut_k(const float* __restrict__ rel_bias, float* __restrict__ lut) {
  int r = blockIdx.x * blockDim.x + threadIdx.x;
  if (r >= 4096) return;
  int rel = r - 2048;
  int b = rel > 0 ? 16 : 0;
  int ar = rel < 0 ? -rel : rel;
  int idx;
  if (ar < 8) {
    idx = b + ar;
  } else {
    double t = log((double)ar / 8.0) / log(16.0) * 8.0;
    int lg = 8 + (int)t;
    if (lg > 15) lg = 15;
    idx = b + lg;
  }
  for (int h = 0; h < 16; ++h)
    lut[h * 4096 + r] = rel_bias[idx * 16 + h];
}

// ---------------- combined Q+KV projection GEMM ----------------
// grid (32, 24): y<8 -> Q: n0=y*128, A=hidden, Bt=WqT, scatter Qb[b,h,s,d]
//                y>=8 -> KV: n0=(y-8)*128, A=kvs, Bt=WkvT;
//                  gn<1024 -> Kb[b,h,k,d]; gn>=1024 -> Vt[b,h,d,k] (packed)
#define LDA 44  // padded fp32->bf16 A rows: 2-way banks, 8B-aligned
__global__ __launch_bounds__(256) void gemm_qkv_k(const float* __restrict__ hidden,
                                                  const float* __restrict__ kvs,
                                                  const bf16* __restrict__ WqT,
                                                  const bf16* __restrict__ WkvT,
                                                  bf16* __restrict__ Qb,
                                                  bf16* __restrict__ Kb,
                                                  bf16* __restrict__ Vt) {
  __shared__ __align__(16) bf16 As[128 * LDA];
  __shared__ __align__(16) bf16 Bs[128 * 32];
  const int tid = threadIdx.x;
  const int lane = tid & 63;
  const int w = tid >> 6;
  const int wm = (w >> 1) * 64;
  const int wn = (w & 1) * 64;
  const int l15 = lane & 15;
  const int quad = lane >> 4;
  const int srow = lane >> 2;
  const int skg = lane & 3;

  const bool isQ = blockIdx.y < 8;
  const float* A = isQ ? hidden : kvs;
  const bf16* Bt = isQ ? WqT : WkvT;
  const int n0 = (isQ ? blockIdx.y : blockIdx.y - 8) * 128;
  const int m0 = blockIdx.x * 128;

  f32x4 acc[4][4];
#pragma unroll
  for (int i = 0; i < 4; ++i)
#pragma unroll
    for (int j = 0; j < 4; ++j) acc[i][j] = (f32x4){0.f, 0.f, 0.f, 0.f};

  for (int k0 = 0; k0 < 1024; k0 += 32) {
    __syncthreads();
    // B (weights) via async16 (m97 pattern, unpadded 32-wide rows)
#pragma unroll
    for (int rep = 0; rep < 2; ++rep) {
      int seg = w * 2 + rep;
      async16(Bt + (size_t)(n0 + seg * 16 + srow) * 1024 + k0 + skg * 8, Bs + seg * 512);
    }
    // A fp32 -> bf16 repack into padded rows
#pragma unroll
    for (int rep = 0; rep < 2; ++rep) {
      int slot = tid + rep * 256;
      int row = slot >> 2, kg = slot & 3;
      const float* pa = A + (size_t)(m0 + row) * 1024 + k0 + kg * 8;
      float4 a0 = *(const float4*)pa;
      float4 a1 = *(const float4*)(pa + 4);
      bf16x4 lo, hi;
      lo[0] = f2b(a0.x); lo[1] = f2b(a0.y); lo[2] = f2b(a0.z); lo[3] = f2b(a0.w);
      hi[0] = f2b(a1.x); hi[1] = f2b(a1.y); hi[2] = f2b(a1.z); hi[3] = f2b(a1.w);
      bf16* dst = As + row * LDA + kg * 8;
      *(bf16x4*)dst = lo;
      *(bf16x4*)(dst + 4) = hi;
    }
    __syncthreads();
    bf16x8 af[4], bfr[4];
#pragma unroll
    for (int i = 0; i < 4; ++i)
      af[i] = ld16(As + (wm + i * 16 + l15) * LDA + quad * 8);
#pragma unroll
    for (int j = 0; j < 4; ++j)
      bfr[j] = *(const bf16x8*)(Bs + (wn + j * 16 + l15) * 32 + quad * 8);
#pragma unroll
    for (int i = 0; i < 4; ++i)
#pragma unroll
      for (int j = 0; j < 4; ++j)
        acc[i][j] = __builtin_amdgcn_mfma_f32_16x16x32_bf16(af[i], bfr[j], acc[i][j], 0, 0, 0);
  }

  // epilogue: C/D layout col=lane&15, row=quad*4+reg
  if (!isQ && n0 >= 1024) {  // V -> transposed [b,h,d,k], pack 4 consecutive k
#pragma unroll
    for (int i = 0; i < 4; ++i) {
      int gmb = m0 + wm + i * 16 + quad * 4;
      int b = gmb >> 11, kp = gmb & 2047;
#pragma unroll
      for (int j = 0; j < 4; ++j) {
        int gn = n0 + wn + j * 16 + l15;
        int h = (gn >> 6) & 15, d = gn & 63;
        us4 pk;
#pragma unroll
        for (int r = 0; r < 4; ++r) pk[r] = b2u(acc[i][j][r]);
        *(us4*)(Vt + ((((size_t)b * 16 + h) * 64 + d) << 11) + kp) = pk;
      }
    }
    return;
  }
#pragma unroll
  for (int i = 0; i < 4; ++i) {
#pragma unroll
    for (int j = 0; j < 4; ++j) {
#pragma unroll
      for (int r = 0; r < 4; ++r) {
        int gm = m0 + wm + i * 16 + quad * 4 + r;
        int gn = n0 + wn + j * 16 + l15;
        bf16 v = __float2bfloat16(acc[i][j][r]);
        int b = gm >> 11, s = gm & 2047;
        int h = (gn >> 6) & 15, d = gn & 63;
        bf16* dst = isQ ? Qb : Kb;
        dst[((((size_t)b * 16 + h) * 2048 + s) << 6) + d] = v;
      }
    }
  }
}

// ---------------- O projection: out[M][N] = Ob * WoT^T (fp32 out) ----------------
__global__ __launch_bounds__(256) void gemm_o_k(const bf16* __restrict__ A,
                                                const bf16* __restrict__ Bt,
                                                float* __restrict__ C0) {
  __shared__ __align__(16) bf16 As[128 * 32];
  __shared__ __align__(16) bf16 Bs[128 * 32];
  const int tid = threadIdx.x;
  const int lane = tid & 63;
  const int w = tid >> 6;
  const int wm = (w >> 1) * 64;
  const int wn = (w & 1) * 64;
  const int m0 = blockIdx.x * 128;
  const int n0 = blockIdx.y * 128;
  const int l15 = lane & 15;
  const int quad = lane >> 4;
  const int srow = lane >> 2;
  const int skg = lane & 3;

  f32x4 acc[4][4];
#pragma unroll
  for (int i = 0; i < 4; ++i)
#pragma unroll
    for (int j = 0; j < 4; ++j) acc[i][j] = (f32x4){0.f, 0.f, 0.f, 0.f};

  for (int k0 = 0; k0 < 1024; k0 += 32) {
    __syncthreads();
#pragma unroll
    for (int rep = 0; rep < 2; ++rep) {
      int seg = w * 2 + rep;
      async16(A + (size_t)(m0 + seg * 16 + srow) * 1024 + k0 + skg * 8, As + seg * 512);
      async16(Bt + (size_t)(n0 + seg * 16 + srow) * 1024 + k0 + skg * 8, Bs + seg * 512);
    }
    __syncthreads();
    bf16x8 af[4], bfr[4];
#pragma unroll
    for (int i = 0; i < 4; ++i)
      af[i] = *(const bf16x8*)(As + (wm + i * 16 + l15) * 32 + quad * 8);
#pragma unroll
    for (int j = 0; j < 4; ++j)
      bfr[j] = *(const bf16x8*)(Bs + (wn + j * 16 + l15) * 32 + quad * 8);
#pragma unroll
    for (int i = 0; i < 4; ++i)
#pragma unroll
      for (int j = 0; j < 4; ++j)
        acc[i][j] = __builtin_amdgcn_mfma_f32_16x16x32_bf16(af[i], bfr[j], acc[i][j], 0, 0, 0);
  }
#pragma unroll
  for (int i = 0; i < 4; ++i)
#pragma unroll
    for (int j = 0; j < 4; ++j)
#pragma unroll
      for (int r = 0; r < 4; ++r) {
        int gm = m0 + wm + i * 16 + quad * 4 + r;
        int gn = n0 + wn + j * 16 + l15;
        C0[(size_t)gm * 1024 + gn] = acc[i][j][r];
      }
}

// ---------------- fused attention, transposed-S formulation ----------------
// grid (16, 32), 256 threads = 4 waves; wave w owns q-strip [qb+w*32, +32)
// S^T = K·Q^T (mfma 32x32x16): lane owns ONE q (col=lane&31) -> scalar softmax state
// P stored packed to Ps[q][k]; O^T = V^T·P^T -> col=q again (no shuffles for rescale)
#define STK 68  // Ks/Vs/Ps row stride: 2-way banks, 8B-aligned rows
__global__ __launch_bounds__(256) void attn_k(const bf16* __restrict__ Qb,
                                              const bf16* __restrict__ Kb,
                                              const bf16* __restrict__ Vt,
                                              const float* __restrict__ lut,
                                              bf16* __restrict__ Ob) {
  __shared__ __align__(16) bf16 Ks[64 * STK];   // [k][d]
  __shared__ __align__(16) bf16 Vs[64 * STK];   // [d][k]
  __shared__ __align__(16) bf16 Ps[128 * STK];  // [q][k]
  __shared__ float lbias[2180];

  const int tid = threadIdx.x;
  const int lane = tid & 63;
  const int w = tid >> 6;
  const int q31 = lane & 31;
  const int half = lane >> 5;  // 0/1

  const int qt = blockIdx.x;  // 0..15
  const int bh = blockIdx.y;  // 0..31
  const int h = bh & 15, b = bh >> 4;
  const int qb = qt * 128;

  // bias slice: lbias[x] = lut[h*4096 + 1921 - qb + x], x in [0,2176)
  const int gcap = h * 4096 + 4095;
  const int gbase = h * 4096 + 1921 - qb;
  for (int t = tid; t < 2176; t += 256) {
    int gi = gbase + t;
    lbias[t] = lut[gi > gcap ? gcap : gi];
  }

  const size_t base = (size_t)bh * 2048 * 64;   // Qb/Kb rows
  const size_t vbase = (size_t)bh * 64 * 2048;  // Vt rows
  const int qg = qb + w * 32 + q31;             // this lane's q row

  // Q B-frags (B[d][q]): lane needs Q[qg][c*16 + half*8 + j] -- contiguous global
  bf16x8 qf[4];
#pragma unroll
  for (int c = 0; c < 4; ++c)
    qf[c] = *(const bf16x8*)(Qb + base + (size_t)qg * 64 + c * 16 + half * 8);

  f32x16 oacc[2];
#pragma unroll
  for (int dj = 0; dj < 2; ++dj)
#pragma unroll
    for (int r = 0; r < 16; ++r) oacc[dj][r] = 0.f;
  float m_run = -INFINITY, l_run = 0.f;

  bf16* prow = Ps + (w * 32 + q31) * STK;  // wave-private q row

  for (int kt = 0; kt < 2048; kt += 64) {
    __syncthreads();
    // stage K [64k][64d] and V^T [64d][64k] (16B global loads, 8B LDS writes)
#pragma unroll
    for (int rep = 0; rep < 2; ++rep) {
      int slot = tid + rep * 256;  // 0..511
      int rr = slot >> 3, cg = slot & 7;
      uint4 kv = *(const uint4*)(Kb + base + (size_t)(kt + rr) * 64 + cg * 8);
      st16(Ks + rr * STK + cg * 8, kv);
      uint4 vv = *(const uint4*)(Vt + vbase + (size_t)rr * 2048 + kt + cg * 8);
      st16(Vs + rr * STK + cg * 8, vv);
    }
    __syncthreads();

    // S^T = K·Q^T : rows k (2 Mtiles), cols q; contraction d = 4 chunks
    f32x16 sacc[2];
#pragma unroll
    for (int mt = 0; mt < 2; ++mt) {
#pragma unroll
      for (int r = 0; r < 16; ++r) sacc[mt][r] = 0.f;
#pragma unroll
      for (int c = 0; c < 4; ++c) {
        bf16x8 kf = ld16(Ks + (mt * 32 + q31) * STK + c * 16 + half * 8);
        sacc[mt] = __builtin_amdgcn_mfma_f32_32x32x16_bf16(kf, qf[c], sacc[mt], 0, 0, 0);
      }
    }

    // bias add + per-lane max (lane owns one q; rows are k packs of 4)
    const int xoff = kt + 127 - w * 32 - q31 + 4 * half;
    float mx = -INFINITY;
#pragma unroll
    for (int mt = 0; mt < 2; ++mt)
#pragma unroll
      for (int g = 0; g < 4; ++g) {
        int x0 = xoff + mt * 32 + 8 * g;
#pragma unroll
        for (int rr = 0; rr < 4; ++rr) {
          float s = sacc[mt][4 * g + rr] + lbias[x0 + rr];
          sacc[mt][4 * g + rr] = s;
          mx = fmaxf(mx, s);
        }
      }
    mx = fmaxf(mx, __shfl_xor(mx, 32));
    float mnew = fmaxf(m_run, mx);
    float alpha = __expf(m_run - mnew);
    m_run = mnew;
    float sum = 0.f;
#pragma unroll
    for (int mt = 0; mt < 2; ++mt)
#pragma unroll
      for (int r = 0; r < 16; ++r) {
        float p = __expf(sacc[mt][r] - mnew);
        sacc[mt][r] = p;
        sum += p;
      }
    sum += __shfl_xor(sum, 32);
    l_run = l_run * alpha + sum;

    // P -> Ps[q][k], packed b64 (4 consecutive k per reg-quad)
#pragma unroll
    for (int mt = 0; mt < 2; ++mt)
#pragma unroll
      for (int g = 0; g < 4; ++g) {
        us4 pk;
#pragma unroll
        for (int rr = 0; rr < 4; ++rr) pk[rr] = b2u(sacc[mt][4 * g + rr]);
        *(us4*)(prow + mt * 32 + 8 * g + 4 * half) = pk;
      }

    // rescale O (per-lane scalar alpha)
#pragma unroll
    for (int dj = 0; dj < 2; ++dj)
#pragma unroll
      for (int r = 0; r < 16; ++r) oacc[dj][r] *= alpha;

    // O^T += V^T·P^T : A from Vs rows, B from own Ps row (both contiguous)
    bf16x8 pf[4];
#pragma unroll
    for (int c = 0; c < 4; ++c) pf[c] = ld16(prow + c * 16 + half * 8);
#pragma unroll
    for (int dj = 0; dj < 2; ++dj)
#pragma unroll
      for (int c = 0; c < 4; ++c) {
        bf16x8 vf = ld16(Vs + (dj * 32 + q31) * STK + c * 16 + half * 8);
        oacc[dj] = __builtin_amdgcn_mfma_f32_32x32x16_bf16(vf, pf[c], oacc[dj], 0, 0, 0);
      }
  }

  // epilogue: O[qg][d] = O^T/l, packed 8B stores (4 consecutive d per reg-quad)
  float inv = 1.0f / l_run;
  float* dummy;
  (void)dummy;
#pragma unroll
  for (int dj = 0; dj < 2; ++dj)
#pragma unroll
    for (int g = 0; g < 4; ++g) {
      us4 pk;
#pragma unroll
      for (int rr = 0; rr < 4; ++rr) pk[rr] = b2u(oacc[dj][4 * g + rr] * inv);
      int d0 = dj * 32 + 8 * g + 4 * half;
      *(us4*)(Ob + ((size_t)(b * 2048 + qg)) * 1024 + h * 64 + d0) = pk;
    }
}

// ---------------- launch ----------------
extern "C" void kernel_launch(void* const* d_in, const int* in_sizes, int n_in,
                              void* d_out, int out_size, void* d_ws, size_t ws_size,
                              hipStream_t stream) {
  const float* hidden = (const float*)d_in[0];
  const float* kvs    = (const float*)d_in[1];
  const float* Wq     = (const float*)d_in[2];
  const float* Wkv    = (const float*)d_in[3];
  const float* Wo     = (const float*)d_in[4];
  const float* relb   = (const float*)d_in[5];
  float* out = (float*)d_out;

  char* ws = (char*)d_ws;
  bf16* WqT  = (bf16*)(ws + (size_t)0);           // 2 MB
  bf16* WkvT = (bf16*)(ws + ((size_t)2 << 20));   // 4 MB
  bf16* WoT  = (bf16*)(ws + ((size_t)6 << 20));   // 2 MB
  bf16* Ob   = (bf16*)(ws + ((size_t)8 << 20));   // 8 MB [B,S,E]
  bf16* Qb   = (bf16*)(ws + ((size_t)16 << 20));  // 8 MB [B,H,S,D]
  bf16* Kb   = (bf16*)(ws + ((size_t)24 << 20));  // 8 MB [B,H,K,D]
  bf16* Vt   = (bf16*)(ws + ((size_t)32 << 20));  // 8 MB [B,H,D,K]
  float* LUT = (float*)(ws + ((size_t)40 << 20)); // 256 KB

  dim3 tb(32, 8);
  transpose_cast_k<<<dim3(32, 32), tb, 0, stream>>>(Wq, WqT, 1024, 1024);
  transpose_cast_k<<<dim3(64, 32), tb, 0, stream>>>(Wkv, WkvT, 1024, 2048);
  transpose_cast_k<<<dim3(32, 32), tb, 0, stream>>>(Wo, WoT, 1024, 1024);
  bias_lut_k<<<16, 256, 0, stream>>>(relb, LUT);

  // Q, K, V projections in one 768-block dispatch (3 blocks/CU)
  gemm_qkv_k<<<dim3(32, 24), 256, 0, stream>>>(hidden, kvs, WqT, WkvT, Qb, Kb, Vt);
  // attention -> Ob
  attn_k<<<dim3(16, 32), 256, 0, stream>>>(Qb, Kb, Vt, LUT, Ob);
  // out = Ob @ Wo (fp32)
  gemm_o_k<<<dim3(32, 8), 256, 0, stream>>>(Ob, WoT, out);
}

// Round 5
// 252.996 us; speedup vs baseline: 1.3496x; 1.0753x over previous
//
#include <hip/hip_runtime.h>
#include <hip/hip_bf16.h>
#include <math.h>

typedef __hip_bfloat16 bf16;
typedef __bf16 bf16x4 __attribute__((ext_vector_type(4)));
typedef __bf16 bf16x8 __attribute__((ext_vector_type(8)));
typedef float f32x4 __attribute__((ext_vector_type(4)));
typedef float f32x16 __attribute__((ext_vector_type(16)));
typedef unsigned short us4 __attribute__((ext_vector_type(4)));

#define LOG2E 1.44269504088896340736f

#if defined(__has_builtin)
#if __has_builtin(__builtin_amdgcn_exp2f)
#define EXP2(x) __builtin_amdgcn_exp2f(x)
#else
#define EXP2(x) exp2f(x)
#endif
#else
#define EXP2(x) exp2f(x)
#endif

__device__ inline __bf16 f2b(float f) {
  __hip_bfloat16 h = __float2bfloat16(f);
  return *reinterpret_cast<__bf16*>(&h);
}
__device__ inline unsigned short b2u(float f) {  // RNE (epilogues, cold)
  __hip_bfloat16 h = __float2bfloat16(f);
  return *reinterpret_cast<unsigned short*>(&h);
}
__device__ inline unsigned short b2u_fast(float f) {  // round-half-up (hot loop)
  union { float f; unsigned u; } v;
  v.f = f;
  return (unsigned short)((v.u + 0x8000u) >> 16);
}
// 16B logical LDS read as two 8B reads (2-way-bank-friendly padded strides)
__device__ inline bf16x8 ld16(const bf16* p) {
  bf16x4 lo = *(const bf16x4*)p;
  bf16x4 hi = *(const bf16x4*)(p + 4);
  return __builtin_shufflevector(lo, hi, 0, 1, 2, 3, 4, 5, 6, 7);
}
__device__ inline void st16(bf16* p, uint4 v) {
  *(uint2*)p = make_uint2(v.x, v.y);
  *(uint2*)(p + 4) = make_uint2(v.z, v.w);
}
// async global->LDS, 16B/lane, lds addr = wave-uniform base + lane*16
__device__ inline void async16(const bf16* g, bf16* l) {
  __builtin_amdgcn_global_load_lds(
      (const __attribute__((address_space(1))) unsigned int*)g,
      (__attribute__((address_space(3))) unsigned int*)l, 16, 0, 0);
}

// ---------------- fp32 -> bf16 cast ----------------
__global__ void cast_k(const float* __restrict__ in, bf16* __restrict__ out, int n) {
  int i = (blockIdx.x * 256 + threadIdx.x) * 8;
  if (i >= n) return;
  float4 a0 = *(const float4*)(in + i);
  float4 a1 = *(const float4*)(in + i + 4);
  bf16x8 v;
  v[0] = f2b(a0.x); v[1] = f2b(a0.y); v[2] = f2b(a0.z); v[3] = f2b(a0.w);
  v[4] = f2b(a1.x); v[5] = f2b(a1.y); v[6] = f2b(a1.z); v[7] = f2b(a1.w);
  *(bf16x8*)(out + i) = v;
}

// ---------------- transpose + cast: out[c][r] = bf16(in[r][c]) ----------------
__global__ void transpose_cast_k(const float* __restrict__ in, bf16* __restrict__ out,
                                 int rows, int cols) {
  __shared__ float tile[32][33];
  int c0 = blockIdx.x * 32;
  int r0 = blockIdx.y * 32;
  int tx = threadIdx.x;
  int ty = threadIdx.y;
  for (int i = ty; i < 32; i += 8)
    tile[i][tx] = in[(size_t)(r0 + i) * cols + c0 + tx];
  __syncthreads();
  for (int i = ty; i < 32; i += 8)
    out[(size_t)(c0 + i) * rows + r0 + tx] = __float2bfloat16(tile[tx][i]);
}

// ---------------- T5 bias LUT (f64 bucketing = np ref), pre-scaled by log2e ----------------
__global__ void bias_lut_k(const float* __restrict__ rel_bias, float* __restrict__ lut) {
  int r = blockIdx.x * blockDim.x + threadIdx.x;
  if (r >= 4096) return;
  int rel = r - 2048;
  int b = rel > 0 ? 16 : 0;
  int ar = rel < 0 ? -rel : rel;
  int idx;
  if (ar < 8) {
    idx = b + ar;
  } else {
    double t = log((double)ar / 8.0) / log(16.0) * 8.0;
    int lg = 8 + (int)t;
    if (lg > 15) lg = 15;
    idx = b + lg;
  }
  for (int h = 0; h < 16; ++h)
    lut[h * 4096 + r] = rel_bias[idx * 16 + h] * LOG2E;
}

// ---------------- fused Q+KV projection GEMM (pure async16, bf16 A) ----------------
// grid (32, 24): y<8 -> Q (scaled by log2e) -> Qb[b,h,s,d]
//                y>=8 -> KV: gn<1024 -> Kb[b,h,k,d]; gn>=1024 -> Vt[b,h,d,k]
__global__ __launch_bounds__(256) void gemm_qkv_k(const bf16* __restrict__ hbf,
                                                  const bf16* __restrict__ kbf,
                                                  const bf16* __restrict__ WqT,
                                                  const bf16* __restrict__ WkvT,
                                                  bf16* __restrict__ Qb,
                                                  bf16* __restrict__ Kb,
                                                  bf16* __restrict__ Vt) {
  __shared__ __align__(16) bf16 As[128 * 32];
  __shared__ __align__(16) bf16 Bs[128 * 32];
  const int tid = threadIdx.x;
  const int lane = tid & 63;
  const int w = tid >> 6;
  const int wm = (w >> 1) * 64;
  const int wn = (w & 1) * 64;
  const int l15 = lane & 15;
  const int quad = lane >> 4;
  const int srow = lane >> 2;
  const int skg = lane & 3;

  const bool isQ = blockIdx.y < 8;
  const bf16* A = isQ ? hbf : kbf;
  const bf16* Bt = isQ ? WqT : WkvT;
  const int n0 = (isQ ? blockIdx.y : blockIdx.y - 8) * 128;
  const int m0 = blockIdx.x * 128;

  f32x4 acc[4][4];
#pragma unroll
  for (int i = 0; i < 4; ++i)
#pragma unroll
    for (int j = 0; j < 4; ++j) acc[i][j] = (f32x4){0.f, 0.f, 0.f, 0.f};

  for (int k0 = 0; k0 < 1024; k0 += 32) {
    __syncthreads();
#pragma unroll
    for (int rep = 0; rep < 2; ++rep) {
      int seg = w * 2 + rep;
      async16(A + (size_t)(m0 + seg * 16 + srow) * 1024 + k0 + skg * 8, As + seg * 512);
      async16(Bt + (size_t)(n0 + seg * 16 + srow) * 1024 + k0 + skg * 8, Bs + seg * 512);
    }
    __syncthreads();
    bf16x8 af[4], bfr[4];
#pragma unroll
    for (int i = 0; i < 4; ++i)
      af[i] = *(const bf16x8*)(As + (wm + i * 16 + l15) * 32 + quad * 8);
#pragma unroll
    for (int j = 0; j < 4; ++j)
      bfr[j] = *(const bf16x8*)(Bs + (wn + j * 16 + l15) * 32 + quad * 8);
#pragma unroll
    for (int i = 0; i < 4; ++i)
#pragma unroll
      for (int j = 0; j < 4; ++j)
        acc[i][j] = __builtin_amdgcn_mfma_f32_16x16x32_bf16(af[i], bfr[j], acc[i][j], 0, 0, 0);
  }

  // epilogue: C/D layout col=lane&15, row=quad*4+reg
  if (!isQ && n0 >= 1024) {  // V -> [b,h,d,k], 4 consecutive k per 8B store
#pragma unroll
    for (int i = 0; i < 4; ++i) {
      int gmb = m0 + wm + i * 16 + quad * 4;
      int b = gmb >> 11, kp = gmb & 2047;
#pragma unroll
      for (int j = 0; j < 4; ++j) {
        int gn = n0 + wn + j * 16 + l15;
        int h = (gn >> 6) & 15, d = gn & 63;
        us4 pk;
#pragma unroll
        for (int r = 0; r < 4; ++r) pk[r] = b2u(acc[i][j][r]);
        *(us4*)(Vt + ((((size_t)b * 16 + h) * 64 + d) << 11) + kp) = pk;
      }
    }
    return;
  }
  const float scale = isQ ? LOG2E : 1.0f;
#pragma unroll
  for (int i = 0; i < 4; ++i)
#pragma unroll
    for (int j = 0; j < 4; ++j)
#pragma unroll
      for (int r = 0; r < 4; ++r) {
        int gm = m0 + wm + i * 16 + quad * 4 + r;
        int gn = n0 + wn + j * 16 + l15;
        bf16 v = __float2bfloat16(acc[i][j][r] * scale);
        int b = gm >> 11, s = gm & 2047;
        int h = (gn >> 6) & 15, d = gn & 63;
        bf16* dst = isQ ? Qb : Kb;
        dst[((((size_t)b * 16 + h) * 2048 + s) << 6) + d] = v;
      }
}

// ---------------- O projection: out[4096][1024] = Ob * WoT^T, 128x64 tiles ----------------
__global__ __launch_bounds__(256) void gemm_o_k(const bf16* __restrict__ A,
                                                const bf16* __restrict__ Bt,
                                                float* __restrict__ C0) {
  __shared__ __align__(16) bf16 As[128 * 32];
  __shared__ __align__(16) bf16 Bs[64 * 32];
  const int tid = threadIdx.x;
  const int lane = tid & 63;
  const int w = tid >> 6;
  const int wm = w * 32;
  const int m0 = blockIdx.x * 128;
  const int n0 = blockIdx.y * 64;
  const int l15 = lane & 15;
  const int quad = lane >> 4;
  const int srow = lane >> 2;
  const int skg = lane & 3;

  f32x4 acc[2][4];
#pragma unroll
  for (int i = 0; i < 2; ++i)
#pragma unroll
    for (int j = 0; j < 4; ++j) acc[i][j] = (f32x4){0.f, 0.f, 0.f, 0.f};

  for (int k0 = 0; k0 < 1024; k0 += 32) {
    __syncthreads();
#pragma unroll
    for (int rep = 0; rep < 2; ++rep) {
      int seg = w * 2 + rep;
      async16(A + (size_t)(m0 + seg * 16 + srow) * 1024 + k0 + skg * 8, As + seg * 512);
    }
    async16(Bt + (size_t)(n0 + w * 16 + srow) * 1024 + k0 + skg * 8, Bs + w * 512);
    __syncthreads();
    bf16x8 af[2], bfr[4];
#pragma unroll
    for (int i = 0; i < 2; ++i)
      af[i] = *(const bf16x8*)(As + (wm + i * 16 + l15) * 32 + quad * 8);
#pragma unroll
    for (int j = 0; j < 4; ++j)
      bfr[j] = *(const bf16x8*)(Bs + (j * 16 + l15) * 32 + quad * 8);
#pragma unroll
    for (int i = 0; i < 2; ++i)
#pragma unroll
      for (int j = 0; j < 4; ++j)
        acc[i][j] = __builtin_amdgcn_mfma_f32_16x16x32_bf16(af[i], bfr[j], acc[i][j], 0, 0, 0);
  }
#pragma unroll
  for (int i = 0; i < 2; ++i)
#pragma unroll
    for (int j = 0; j < 4; ++j)
#pragma unroll
      for (int r = 0; r < 4; ++r) {
        int gm = m0 + wm + i * 16 + quad * 4 + r;
        int gn = n0 + j * 16 + l15;
        C0[(size_t)gm * 1024 + gn] = acc[i][j][r];
      }
}

// ---------------- fused attention, transposed-S, 128q x 128k tiles ----------------
// grid (16, 32), 4 waves; wave w owns q-strip [qb+w*32, +32); lane owns one q (col)
#define STK 68
#define SVK 136
__global__ __launch_bounds__(256) void attn_k(const bf16* __restrict__ Qb,
                                              const bf16* __restrict__ Kb,
                                              const bf16* __restrict__ Vt,
                                              const float* __restrict__ lut,
                                              bf16* __restrict__ Ob) {
  __shared__ float lbias[2176];
  __shared__ __align__(16) bf16 Ks[128 * STK];   // [k][d]
  __shared__ __align__(16) bf16 Vs[64 * SVK];    // [d][k]
  __shared__ __align__(16) bf16 Ps[128 * SVK];   // [q][k] (wave-private rows)

  const int tid = threadIdx.x;
  const int lane = tid & 63;
  const int w = tid >> 6;
  const int q31 = lane & 31;
  const int half = lane >> 5;

  const int qt = blockIdx.x;  // 0..15
  const int bh = blockIdx.y;  // 0..31
  const int h = bh & 15, b = bh >> 4;
  const int qb = qt * 128;

  // bias slice (log2 domain): lbias[x] = lut[h*4096 + 1921 - qb + x], x in [0,2175)
  const int gbase = h * 4096 + 1921 - qb;
  for (int t = tid; t < 2175; t += 256) lbias[t] = lut[gbase + t];

  const size_t base = (size_t)bh * 2048 * 64;   // Qb/Kb rows
  const size_t vbase = (size_t)bh * 64 * 2048;  // Vt rows
  const int qg = qb + w * 32 + q31;

  // Q B-frags (Q pre-scaled by log2e in projection)
  bf16x8 qf[4];
#pragma unroll
  for (int c = 0; c < 4; ++c)
    qf[c] = *(const bf16x8*)(Qb + base + (size_t)qg * 64 + c * 16 + half * 8);

  f32x16 oacc[2];
#pragma unroll
  for (int dj = 0; dj < 2; ++dj)
#pragma unroll
    for (int r = 0; r < 16; ++r) oacc[dj][r] = 0.f;
  float m_run = -INFINITY, l_run = 0.f;

  bf16* prow = Ps + (w * 32 + q31) * SVK;

  for (int kt = 0; kt < 2048; kt += 128) {
    __syncthreads();  // all waves done reading Ks/Vs from previous tile
    // stage K [128k][64d] -> Ks rows; V^T [64d][128k] -> Vs rows
#pragma unroll
    for (int rep = 0; rep < 4; ++rep) {
      int slot = tid + rep * 256;  // 0..1023
      int kk = slot >> 3, cg = slot & 7;
      uint4 kv = *(const uint4*)(Kb + base + (size_t)(kt + kk) * 64 + cg * 8);
      st16(Ks + kk * STK + cg * 8, kv);
      int d = slot >> 4, c = slot & 15;
      uint4 vv = *(const uint4*)(Vt + vbase + (size_t)d * 2048 + kt + c * 8);
      st16(Vs + d * SVK + c * 8, vv);
    }
    __syncthreads();

    // S^T = K·Q^T : 4 k-Mtiles x (contraction d: 4 chunks)
    f32x16 sacc[4];
#pragma unroll
    for (int mt = 0; mt < 4; ++mt) {
#pragma unroll
      for (int r = 0; r < 16; ++r) sacc[mt][r] = 0.f;
#pragma unroll
      for (int c = 0; c < 4; ++c) {
        bf16x8 kf = ld16(Ks + (mt * 32 + q31) * STK + c * 16 + half * 8);
        sacc[mt] = __builtin_amdgcn_mfma_f32_32x32x16_bf16(kf, qf[c], sacc[mt], 0, 0, 0);
      }
    }

    // bias + per-lane max (lane owns one q)
    const int xbase = kt + 127 + 4 * half - w * 32 - q31;
    float mx = -INFINITY;
#pragma unroll
    for (int mt = 0; mt < 4; ++mt)
#pragma unroll
      for (int g = 0; g < 4; ++g) {
        int x0 = xbase + mt * 32 + 8 * g;
#pragma unroll
        for (int rr = 0; rr < 4; ++rr) {
          float s = sacc[mt][4 * g + rr] + lbias[x0 + rr];
          sacc[mt][4 * g + rr] = s;
          mx = fmaxf(mx, s);
        }
      }
    mx = fmaxf(mx, __shfl_xor(mx, 32));
    float mnew = fmaxf(m_run, mx);
    float alpha = EXP2(m_run - mnew);
    m_run = mnew;
    float sum = 0.f;
#pragma unroll
    for (int mt = 0; mt < 4; ++mt)
#pragma unroll
      for (int r = 0; r < 16; ++r) {
        float p = EXP2(sacc[mt][r] - mnew);
        sacc[mt][r] = p;
        sum += p;
      }
    sum += __shfl_xor(sum, 32);
    l_run = l_run * alpha + sum;

    // P -> Ps[q][k] packed 8B (wave-private rows: no barrier needed before re-read)
#pragma unroll
    for (int mt = 0; mt < 4; ++mt)
#pragma unroll
      for (int g = 0; g < 4; ++g) {
        us4 pk;
#pragma unroll
        for (int rr = 0; rr < 4; ++rr) pk[rr] = b2u_fast(sacc[mt][4 * g + rr]);
        *(us4*)(prow + mt * 32 + 8 * g + 4 * half) = pk;
      }

    // rescale O
#pragma unroll
    for (int dj = 0; dj < 2; ++dj)
#pragma unroll
      for (int r = 0; r < 16; ++r) oacc[dj][r] *= alpha;

    // O^T += V^T·P^T (contraction k: 8 chunks)
    bf16x8 pf[8];
#pragma unroll
    for (int c = 0; c < 8; ++c) pf[c] = ld16(prow + c * 16 + half * 8);
#pragma unroll
    for (int dj = 0; dj < 2; ++dj)
#pragma unroll
      for (int c = 0; c < 8; ++c) {
        bf16x8 vf = ld16(Vs + (dj * 32 + q31) * SVK + c * 16 + half * 8);
        oacc[dj] = __builtin_amdgcn_mfma_f32_32x32x16_bf16(vf, pf[c], oacc[dj], 0, 0, 0);
      }
  }

  // epilogue: O[qg][d] = O^T/l, 8B packed stores
  float inv = 1.0f / l_run;
#pragma unroll
  for (int dj = 0; dj < 2; ++dj)
#pragma unroll
    for (int g = 0; g < 4; ++g) {
      us4 pk;
#pragma unroll
      for (int rr = 0; rr < 4; ++rr) pk[rr] = b2u(oacc[dj][4 * g + rr] * inv);
      int d0 = dj * 32 + 8 * g + 4 * half;
      *(us4*)(Ob + ((size_t)(b * 2048 + qg)) * 1024 + h * 64 + d0) = pk;
    }
}

// ---------------- launch ----------------
extern "C" void kernel_launch(void* const* d_in, const int* in_sizes, int n_in,
                              void* d_out, int out_size, void* d_ws, size_t ws_size,
                              hipStream_t stream) {
  const float* hidden = (const float*)d_in[0];
  const float* kvs    = (const float*)d_in[1];
  const float* Wq     = (const float*)d_in[2];
  const float* Wkv    = (const float*)d_in[3];
  const float* Wo     = (const float*)d_in[4];
  const float* relb   = (const float*)d_in[5];
  float* out = (float*)d_out;

  char* ws = (char*)d_ws;
  bf16* WqT  = (bf16*)(ws + (size_t)0);           // 2 MB
  bf16* WkvT = (bf16*)(ws + ((size_t)2 << 20));   // 4 MB
  bf16* WoT  = (bf16*)(ws + ((size_t)6 << 20));   // 2 MB
  bf16* Ob   = (bf16*)(ws + ((size_t)8 << 20));   // 8 MB [B,S,E]
  bf16* hbf  = Ob;                                //   aliased: dead after gemm_qkv
  bf16* Qb   = (bf16*)(ws + ((size_t)16 << 20));  // 8 MB [B,H,S,D]
  bf16* Kb   = (bf16*)(ws + ((size_t)24 << 20));  // 8 MB [B,H,K,D]
  bf16* Vt   = (bf16*)(ws + ((size_t)32 << 20));  // 8 MB [B,H,D,K]
  float* LUT = (float*)(ws + ((size_t)40 << 20)); // 256 KB
  bf16* kbf  = (bf16*)d_out;                      // 8 MB scratch in d_out (16 MB), overwritten by gemm_o

  dim3 tb(32, 8);
  transpose_cast_k<<<dim3(32, 32), tb, 0, stream>>>(Wq, WqT, 1024, 1024);
  transpose_cast_k<<<dim3(64, 32), tb, 0, stream>>>(Wkv, WkvT, 1024, 2048);
  transpose_cast_k<<<dim3(32, 32), tb, 0, stream>>>(Wo, WoT, 1024, 1024);
  bias_lut_k<<<16, 256, 0, stream>>>(relb, LUT);
  cast_k<<<2048, 256, 0, stream>>>(hidden, hbf, 4194304);
  cast_k<<<2048, 256, 0, stream>>>(kvs, kbf, 4194304);

  // Q (x log2e), K, V projections
  gemm_qkv_k<<<dim3(32, 24), 256, 0, stream>>>(hbf, kbf, WqT, WkvT, Qb, Kb, Vt);
  // attention -> Ob (overwrites hbf region, safe: hbf consumed)
  attn_k<<<dim3(16, 32), 256, 0, stream>>>(Qb, Kb, Vt, LUT, Ob);
  // out = Ob @ Wo (overwrites kbf region, safe: kbf consumed)
  gemm_o_k<<<dim3(32, 16), 256, 0, stream>>>(Ob, WoT, out);
}

// Round 6
// 233.937 us; speedup vs baseline: 1.4596x; 1.0815x over previous
//
#include <hip/hip_runtime.h>
#include <hip/hip_bf16.h>
#include <math.h>

typedef __hip_bfloat16 bf16;
typedef __bf16 bf16x4 __attribute__((ext_vector_type(4)));
typedef __bf16 bf16x8 __attribute__((ext_vector_type(8)));
typedef float f32x4 __attribute__((ext_vector_type(4)));
typedef float f32x16 __attribute__((ext_vector_type(16)));
typedef unsigned short us4 __attribute__((ext_vector_type(4)));

#define LOG2E 1.44269504088896340736f

#if defined(__has_builtin)
#if __has_builtin(__builtin_amdgcn_exp2f)
#define EXP2(x) __builtin_amdgcn_exp2f(x)
#else
#define EXP2(x) exp2f(x)
#endif
#else
#define EXP2(x) exp2f(x)
#endif

__device__ inline __bf16 f2b(float f) {
  __hip_bfloat16 h = __float2bfloat16(f);
  return *reinterpret_cast<__bf16*>(&h);
}
__device__ inline unsigned short b2u(float f) {  // RNE (cold paths)
  __hip_bfloat16 h = __float2bfloat16(f);
  return *reinterpret_cast<unsigned short*>(&h);
}
__device__ inline unsigned short b2u_fast(float f) {  // round-half-up (hot loop)
  union { float f; unsigned u; } v;
  v.f = f;
  return (unsigned short)((v.u + 0x8000u) >> 16);
}
// 16B logical LDS read as two 8B reads (2-way-bank-friendly padded strides)
__device__ inline bf16x8 ld16(const bf16* p) {
  bf16x4 lo = *(const bf16x4*)p;
  bf16x4 hi = *(const bf16x4*)(p + 4);
  return __builtin_shufflevector(lo, hi, 0, 1, 2, 3, 4, 5, 6, 7);
}
__device__ inline void st16(bf16* p, uint4 v) {
  *(uint2*)p = make_uint2(v.x, v.y);
  *(uint2*)(p + 4) = make_uint2(v.z, v.w);
}
__device__ inline us4 shfl32_us4(us4 v) {
  uint2 u = *(uint2*)&v;
  u.x = __shfl_xor(u.x, 32);
  u.y = __shfl_xor(u.y, 32);
  return *(us4*)&u;
}
__device__ inline bf16x8 mk8(us4 lo, us4 hi) {
  bf16x4 l = *(bf16x4*)&lo;
  bf16x4 h = *(bf16x4*)&hi;
  return __builtin_shufflevector(l, h, 0, 1, 2, 3, 4, 5, 6, 7);
}
// async global->LDS, 16B/lane, lds addr = wave-uniform base + lane*16
__device__ inline void async16(const bf16* g, bf16* l) {
  __builtin_amdgcn_global_load_lds(
      (const __attribute__((address_space(1))) unsigned int*)g,
      (__attribute__((address_space(3))) unsigned int*)l, 16, 0, 0);
}

// ---------------- fused fp32 -> bf16 cast for hidden+kvs ----------------
__global__ void cast2_k(const float* __restrict__ a, const float* __restrict__ b,
                        bf16* __restrict__ oa, bf16* __restrict__ ob) {
  int gid = blockIdx.x * 256 + threadIdx.x;  // grid 4096 blocks
  const float* in = (gid < 524288) ? a : b;
  bf16* out = (gid < 524288) ? oa : ob;
  int i = (gid & 524287) * 8;
  float4 a0 = *(const float4*)(in + i);
  float4 a1 = *(const float4*)(in + i + 4);
  bf16x8 v;
  v[0] = f2b(a0.x); v[1] = f2b(a0.y); v[2] = f2b(a0.z); v[3] = f2b(a0.w);
  v[4] = f2b(a1.x); v[5] = f2b(a1.y); v[6] = f2b(a1.z); v[7] = f2b(a1.w);
  *(bf16x8*)(out + i) = v;
}

// ---------------- fused transpose + cast for all 3 weights ----------------
__global__ void transpose_all_k(const float* __restrict__ Wq, const float* __restrict__ Wkv,
                                const float* __restrict__ Wo, bf16* __restrict__ WqT,
                                bf16* __restrict__ WkvT, bf16* __restrict__ WoT) {
  __shared__ float tile[32][33];
  int z = blockIdx.z;
  const float* in = z == 0 ? Wq : (z == 1 ? Wkv : Wo);
  bf16* out = z == 0 ? WqT : (z == 1 ? WkvT : WoT);
  int cols = z == 1 ? 2048 : 1024;
  int c0 = blockIdx.x * 32;
  if (c0 >= cols) return;
  int r0 = blockIdx.y * 32;
  int tx = threadIdx.x, ty = threadIdx.y;
  for (int i = ty; i < 32; i += 8)
    tile[i][tx] = in[(size_t)(r0 + i) * cols + c0 + tx];
  __syncthreads();
  for (int i = ty; i < 32; i += 8)
    out[(size_t)(c0 + i) * 1024 + r0 + tx] = __float2bfloat16(tile[tx][i]);
}

// ---------------- T5 bias LUT (f64 bucketing = np ref), pre-scaled by log2e ----------------
__global__ void bias_lut_k(const float* __restrict__ rel_bias, float* __restrict__ lut) {
  int r = blockIdx.x * blockDim.x + threadIdx.x;
  if (r >= 4096) return;
  int rel = r - 2048;
  int b = rel > 0 ? 16 : 0;
  int ar = rel < 0 ? -rel : rel;
  int idx;
  if (ar < 8) {
    idx = b + ar;
  } else {
    double t = log((double)ar / 8.0) / log(16.0) * 8.0;
    int lg = 8 + (int)t;
    if (lg > 15) lg = 15;
    idx = b + lg;
  }
  for (int h = 0; h < 16; ++h)
    lut[h * 4096 + r] = rel_bias[idx * 16 + h] * LOG2E;
}

// ---------------- fused Q+KV projection GEMM (pure async16) ----------------
// grid (32, 24): y<8 -> Q (x log2e) -> Qb[b,h,s,d]; y>=8: gn<1024 -> Kb[b,h,k,d],
// gn>=1024 -> Vt[b,h,d,k]. Q/K use swapped-operand MFMA (D^T) for packed epilogue.
__global__ __launch_bounds__(256) void gemm_qkv_k(const bf16* __restrict__ hbf,
                                                  const bf16* __restrict__ kbf,
                                                  const bf16* __restrict__ WqT,
                                                  const bf16* __restrict__ WkvT,
                                                  bf16* __restrict__ Qb,
                                                  bf16* __restrict__ Kb,
                                                  bf16* __restrict__ Vt) {
  __shared__ __align__(16) bf16 As[128 * 32];
  __shared__ __align__(16) bf16 Bs[128 * 32];
  const int tid = threadIdx.x;
  const int lane = tid & 63;
  const int w = tid >> 6;
  const int wm = (w >> 1) * 64;
  const int wn = (w & 1) * 64;
  const int l15 = lane & 15;
  const int quad = lane >> 4;
  const int srow = lane >> 2;
  const int skg = lane & 3;

  const bool isQ = blockIdx.y < 8;
  const bf16* A = isQ ? hbf : kbf;
  const bf16* Bt = isQ ? WqT : WkvT;
  const int n0 = (isQ ? blockIdx.y : blockIdx.y - 8) * 128;
  const int m0 = blockIdx.x * 128;
  const bool isV = (!isQ) && (n0 >= 1024);

  f32x4 acc[4][4];
#pragma unroll
  for (int i = 0; i < 4; ++i)
#pragma unroll
    for (int j = 0; j < 4; ++j) acc[i][j] = (f32x4){0.f, 0.f, 0.f, 0.f};

  for (int k0 = 0; k0 < 1024; k0 += 32) {
    __syncthreads();
#pragma unroll
    for (int rep = 0; rep < 2; ++rep) {
      int seg = w * 2 + rep;
      async16(A + (size_t)(m0 + seg * 16 + srow) * 1024 + k0 + skg * 8, As + seg * 512);
      async16(Bt + (size_t)(n0 + seg * 16 + srow) * 1024 + k0 + skg * 8, Bs + seg * 512);
    }
    __syncthreads();
    bf16x8 af[4], bfr[4];
#pragma unroll
    for (int i = 0; i < 4; ++i)
      af[i] = *(const bf16x8*)(As + (wm + i * 16 + l15) * 32 + quad * 8);
#pragma unroll
    for (int j = 0; j < 4; ++j)
      bfr[j] = *(const bf16x8*)(Bs + (wn + j * 16 + l15) * 32 + quad * 8);
    if (isV) {  // normal: lane regs vary gm (=k of V) for packed V^T store
#pragma unroll
      for (int i = 0; i < 4; ++i)
#pragma unroll
        for (int j = 0; j < 4; ++j)
          acc[i][j] = __builtin_amdgcn_mfma_f32_16x16x32_bf16(af[i], bfr[j], acc[i][j], 0, 0, 0);
    } else {  // swapped: D^T, lane regs vary gn (=d) for packed Q/K store
#pragma unroll
      for (int i = 0; i < 4; ++i)
#pragma unroll
        for (int j = 0; j < 4; ++j)
          acc[i][j] = __builtin_amdgcn_mfma_f32_16x16x32_bf16(bfr[j], af[i], acc[i][j], 0, 0, 0);
    }
  }

  if (isV) {  // V -> [b,h,d,k], 4 consecutive k per 8B store
#pragma unroll
    for (int i = 0; i < 4; ++i) {
      int gmb = m0 + wm + i * 16 + quad * 4;
      int b = gmb >> 11, kp = gmb & 2047;
#pragma unroll
      for (int j = 0; j < 4; ++j) {
        int gn = n0 + wn + j * 16 + l15;
        int h = (gn >> 6) & 15, d = gn & 63;
        us4 pk;
#pragma unroll
        for (int r = 0; r < 4; ++r) pk[r] = b2u(acc[i][j][r]);
        *(us4*)(Vt + ((((size_t)b * 16 + h) * 64 + d) << 11) + kp) = pk;
      }
    }
    return;
  }
  // Q/K swapped epilogue: gm = ..+l15 (s), gn = ..+quad*4+r (d packed)
  const float scale = isQ ? LOG2E : 1.0f;
  bf16* dst = isQ ? Qb : Kb;
#pragma unroll
  for (int i = 0; i < 4; ++i) {
    int gm = m0 + wm + i * 16 + l15;
    int b = gm >> 11, s = gm & 2047;
#pragma unroll
    for (int j = 0; j < 4; ++j) {
      int gn = n0 + wn + j * 16 + quad * 4;
      int h = (gn >> 6) & 15, d0 = gn & 63;
      us4 pk;
#pragma unroll
      for (int r = 0; r < 4; ++r) pk[r] = b2u(acc[i][j][r] * scale);
      *(us4*)(dst + ((((size_t)b * 16 + h) * 2048 + s) << 6) + d0) = pk;
    }
  }
}

// ---------------- O projection: out[4096][1024] = Ob * WoT^T, 128x64 tiles ----------------
// swapped-operand MFMA -> float4 stores
__global__ __launch_bounds__(256) void gemm_o_k(const bf16* __restrict__ A,
                                                const bf16* __restrict__ Bt,
                                                float* __restrict__ C0) {
  __shared__ __align__(16) bf16 As[128 * 32];
  __shared__ __align__(16) bf16 Bs[64 * 32];
  const int tid = threadIdx.x;
  const int lane = tid & 63;
  const int w = tid >> 6;
  const int wm = w * 32;
  const int m0 = blockIdx.x * 128;
  const int n0 = blockIdx.y * 64;
  const int l15 = lane & 15;
  const int quad = lane >> 4;
  const int srow = lane >> 2;
  const int skg = lane & 3;

  f32x4 acc[2][4];
#pragma unroll
  for (int i = 0; i < 2; ++i)
#pragma unroll
    for (int j = 0; j < 4; ++j) acc[i][j] = (f32x4){0.f, 0.f, 0.f, 0.f};

  for (int k0 = 0; k0 < 1024; k0 += 32) {
    __syncthreads();
#pragma unroll
    for (int rep = 0; rep < 2; ++rep) {
      int seg = w * 2 + rep;
      async16(A + (size_t)(m0 + seg * 16 + srow) * 1024 + k0 + skg * 8, As + seg * 512);
    }
    async16(Bt + (size_t)(n0 + w * 16 + srow) * 1024 + k0 + skg * 8, Bs + w * 512);
    __syncthreads();
    bf16x8 af[2], bfr[4];
#pragma unroll
    for (int i = 0; i < 2; ++i)
      af[i] = *(const bf16x8*)(As + (wm + i * 16 + l15) * 32 + quad * 8);
#pragma unroll
    for (int j = 0; j < 4; ++j)
      bfr[j] = *(const bf16x8*)(Bs + (j * 16 + l15) * 32 + quad * 8);
#pragma unroll
    for (int i = 0; i < 2; ++i)
#pragma unroll
      for (int j = 0; j < 4; ++j)
        acc[i][j] = __builtin_amdgcn_mfma_f32_16x16x32_bf16(bfr[j], af[i], acc[i][j], 0, 0, 0);
  }
#pragma unroll
  for (int i = 0; i < 2; ++i) {
    int gm = m0 + wm + i * 16 + l15;
#pragma unroll
    for (int j = 0; j < 4; ++j) {
      int gn = n0 + j * 16 + quad * 4;
      *(f32x4*)(C0 + (size_t)gm * 1024 + gn) = acc[i][j];
    }
  }
}

// ---------------- fused attention, transposed-S, shfl-exchanged P ----------------
// grid (16, 32), 4 waves; wave w owns q-strip [qb+w*32,+32); lane owns one q (col=lane&31)
// C-layout of S^T: k_off = (reg&3)+8*(reg>>2)+4*half. PV B-frag built in-register:
// lane pair (l, l^32) share q; exchange complementary k-quads via shfl_xor(32).
#define STK 68
#define SVK 136
__global__ __launch_bounds__(256) void attn_k(const bf16* __restrict__ Qb,
                                              const bf16* __restrict__ Kb,
                                              const bf16* __restrict__ Vt,
                                              const float* __restrict__ lut,
                                              bf16* __restrict__ Ob) {
  __shared__ float lbias[2176];
  __shared__ __align__(16) bf16 Ks[128 * STK];  // [k][d]
  __shared__ __align__(16) bf16 Vs[64 * SVK];   // [d][k]

  const int tid = threadIdx.x;
  const int lane = tid & 63;
  const int w = tid >> 6;
  const int q31 = lane & 31;
  const int half = lane >> 5;

  const int qt = blockIdx.x;  // 0..15
  const int bh = blockIdx.y;  // 0..31
  const int h = bh & 15, b = bh >> 4;
  const int qb = qt * 128;

  const int gbase = h * 4096 + 1921 - qb;
  for (int t = tid; t < 2175; t += 256) lbias[t] = lut[gbase + t];

  const size_t base = (size_t)bh * 2048 * 64;   // Qb/Kb rows
  const size_t vbase = (size_t)bh * 64 * 2048;  // Vt rows
  const int qg = qb + w * 32 + q31;

  // Q B-frags (pre-scaled by log2e in projection)
  bf16x8 qf[4];
#pragma unroll
  for (int c = 0; c < 4; ++c)
    qf[c] = *(const bf16x8*)(Qb + base + (size_t)qg * 64 + c * 16 + half * 8);

  f32x16 oacc[2];
#pragma unroll
  for (int dj = 0; dj < 2; ++dj)
#pragma unroll
    for (int r = 0; r < 16; ++r) oacc[dj][r] = 0.f;
  float m_run = -INFINITY, l_run = 0.f;

  // prefetch tile 0 staging into registers
  uint4 kreg[4], vreg[4];
#pragma unroll
  for (int rep = 0; rep < 4; ++rep) {
    int slot = tid + rep * 256;
    kreg[rep] = *(const uint4*)(Kb + base + (size_t)(slot >> 3) * 64 + (slot & 7) * 8);
    vreg[rep] = *(const uint4*)(Vt + vbase + (size_t)(slot >> 4) * 2048 + (slot & 15) * 8);
  }

  for (int kt = 0; kt < 2048; kt += 128) {
    __syncthreads();  // all waves done reading Ks/Vs
#pragma unroll
    for (int rep = 0; rep < 4; ++rep) {
      int slot = tid + rep * 256;
      st16(Ks + (slot >> 3) * STK + (slot & 7) * 8, kreg[rep]);
      st16(Vs + (slot >> 4) * SVK + (slot & 15) * 8, vreg[rep]);
    }
    __syncthreads();
    if (kt + 128 < 2048) {  // prefetch next tile; latency hides behind compute
#pragma unroll
      for (int rep = 0; rep < 4; ++rep) {
        int slot = tid + rep * 256;
        kreg[rep] = *(const uint4*)(Kb + base + (size_t)(kt + 128 + (slot >> 3)) * 64 + (slot & 7) * 8);
        vreg[rep] = *(const uint4*)(Vt + vbase + (size_t)(slot >> 4) * 2048 + kt + 128 + (slot & 15) * 8);
      }
    }

    // S^T = K·Q^T : 4 k-Mtiles, contraction over d (4 chunks)
    f32x16 sacc[4];
#pragma unroll
    for (int mt = 0; mt < 4; ++mt) {
#pragma unroll
      for (int r = 0; r < 16; ++r) sacc[mt][r] = 0.f;
#pragma unroll
      for (int c = 0; c < 4; ++c) {
        bf16x8 kf = ld16(Ks + (mt * 32 + q31) * STK + c * 16 + half * 8);
        sacc[mt] = __builtin_amdgcn_mfma_f32_32x32x16_bf16(kf, qf[c], sacc[mt], 0, 0, 0);
      }
    }

    // bias + per-lane max
    const int xbase = kt + 127 + 4 * half - w * 32 - q31;
    float mx = -INFINITY;
#pragma unroll
    for (int mt = 0; mt < 4; ++mt)
#pragma unroll
      for (int g = 0; g < 4; ++g) {
        int x0 = xbase + mt * 32 + 8 * g;
#pragma unroll
        for (int rr = 0; rr < 4; ++rr) {
          float s = sacc[mt][4 * g + rr] + lbias[x0 + rr];
          sacc[mt][4 * g + rr] = s;
          mx = fmaxf(mx, s);
        }
      }
    mx = fmaxf(mx, __shfl_xor(mx, 32));
    float mnew = fmaxf(m_run, mx);
    float alpha = EXP2(m_run - mnew);
    m_run = mnew;
    float sum = 0.f;
#pragma unroll
    for (int mt = 0; mt < 4; ++mt)
#pragma unroll
      for (int r = 0; r < 16; ++r) {
        float p = EXP2(sacc[mt][r] - mnew);
        sacc[mt][r] = p;
        sum += p;
      }
    sum += __shfl_xor(sum, 32);
    l_run = l_run * alpha + sum;

    // pack P quads and exchange across half boundary (no LDS!)
    us4 ownq[4][4], rcv[4][2];
#pragma unroll
    for (int mt = 0; mt < 4; ++mt) {
#pragma unroll
      for (int a = 0; a < 4; ++a) {
        us4 pk;
#pragma unroll
        for (int bb = 0; bb < 4; ++bb) pk[bb] = b2u_fast(sacc[mt][4 * a + bb]);
        ownq[mt][a] = pk;
      }
      // send the quads the partner needs; receive its complementary quads
      us4 s0 = half ? ownq[mt][0] : ownq[mt][1];
      us4 s1 = half ? ownq[mt][2] : ownq[mt][3];
      rcv[mt][0] = shfl32_us4(s0);
      rcv[mt][1] = shfl32_us4(s1);
    }

    // rescale O
#pragma unroll
    for (int dj = 0; dj < 2; ++dj)
#pragma unroll
      for (int r = 0; r < 16; ++r) oacc[dj][r] *= alpha;

    // O^T += V^T·P^T : B-frag for chunk c (mt=c>>1, p=c&1):
    // half=0: {own[2p], rcv[p]}   half=1: {rcv[p], own[2p+1]}
#pragma unroll
    for (int c = 0; c < 8; ++c) {
      int mt = c >> 1, p = c & 1;
      bf16x8 pfc = half ? mk8(rcv[mt][p], ownq[mt][2 * p + 1])
                        : mk8(ownq[mt][2 * p], rcv[mt][p]);
#pragma unroll
      for (int dj = 0; dj < 2; ++dj) {
        bf16x8 vf = ld16(Vs + (dj * 32 + q31) * SVK + c * 16 + half * 8);
        oacc[dj] = __builtin_amdgcn_mfma_f32_32x32x16_bf16(vf, pfc, oacc[dj], 0, 0, 0);
      }
    }
  }

  // epilogue: O[qg][d] = O^T/l, 8B packed stores
  float inv = 1.0f / l_run;
#pragma unroll
  for (int dj = 0; dj < 2; ++dj)
#pragma unroll
    for (int g = 0; g < 4; ++g) {
      us4 pk;
#pragma unroll
      for (int rr = 0; rr < 4; ++rr) pk[rr] = b2u(oacc[dj][4 * g + rr] * inv);
      int d0 = dj * 32 + 8 * g + 4 * half;
      *(us4*)(Ob + ((size_t)(b * 2048 + qg)) * 1024 + h * 64 + d0) = pk;
    }
}

// ---------------- launch ----------------
extern "C" void kernel_launch(void* const* d_in, const int* in_sizes, int n_in,
                              void* d_out, int out_size, void* d_ws, size_t ws_size,
                              hipStream_t stream) {
  const float* hidden = (const float*)d_in[0];
  const float* kvs    = (const float*)d_in[1];
  const float* Wq     = (const float*)d_in[2];
  const float* Wkv    = (const float*)d_in[3];
  const float* Wo     = (const float*)d_in[4];
  const float* relb   = (const float*)d_in[5];
  float* out = (float*)d_out;

  char* ws = (char*)d_ws;
  bf16* WqT  = (bf16*)(ws + (size_t)0);           // 2 MB
  bf16* WkvT = (bf16*)(ws + ((size_t)2 << 20));   // 4 MB
  bf16* WoT  = (bf16*)(ws + ((size_t)6 << 20));   // 2 MB
  bf16* Ob   = (bf16*)(ws + ((size_t)8 << 20));   // 8 MB [B,S,E]
  bf16* hbf  = Ob;                                //   aliased: dead after gemm_qkv
  bf16* Qb   = (bf16*)(ws + ((size_t)16 << 20));  // 8 MB [B,H,S,D]
  bf16* Kb   = (bf16*)(ws + ((size_t)24 << 20));  // 8 MB [B,H,K,D]
  bf16* Vt   = (bf16*)(ws + ((size_t)32 << 20));  // 8 MB [B,H,D,K]
  float* LUT = (float*)(ws + ((size_t)40 << 20)); // 256 KB
  bf16* kbf  = (bf16*)d_out;                      // 8 MB scratch in d_out, overwritten by gemm_o

  transpose_all_k<<<dim3(64, 32, 3), dim3(32, 8), 0, stream>>>(Wq, Wkv, Wo, WqT, WkvT, WoT);
  bias_lut_k<<<16, 256, 0, stream>>>(relb, LUT);
  cast2_k<<<4096, 256, 0, stream>>>(hidden, kvs, hbf, kbf);

  // Q (x log2e), K, V projections
  gemm_qkv_k<<<dim3(32, 24), 256, 0, stream>>>(hbf, kbf, WqT, WkvT, Qb, Kb, Vt);
  // attention -> Ob (overwrites hbf region, safe: hbf consumed)
  attn_k<<<dim3(16, 32), 256, 0, stream>>>(Qb, Kb, Vt, LUT, Ob);
  // out = Ob @ Wo (overwrites kbf region, safe: kbf consumed)
  gemm_o_k<<<dim3(32, 16), 256, 0, stream>>>(Ob, WoT, out);
}